// Round 12
// baseline (368.240 us; speedup 1.0000x reference)
//
#include <hip/hip_runtime.h>
#include <hip/hip_bf16.h>
#include <stdint.h>

#define S_LEN 2688
#define DIM   1536
#define NH    12
#define HD    128
#define QKV_N 4608   // 3*DIM

typedef __attribute__((ext_vector_type(8))) short bf16x8;
typedef __attribute__((ext_vector_type(4))) float f32x4;

__device__ inline ushort f2bf(float f) {
    uint32_t u = __float_as_uint(f);
    uint32_t r = (u + 0x7fffu + ((u >> 16) & 1u)) >> 16;
    return (ushort)r;
}
__device__ inline float bf2f(uint u) { return __uint_as_float(u << 16); }
__device__ inline float fexp2(float x) {           // raw v_exp_f32 (2^x); args
    float r;                                       // bounded by defer-max
    asm("v_exp_f32 %0, %1" : "=v"(r) : "v"(x));
    return r;
}
__device__ inline uint cvtpk(float lo, float hi) { // 2xf32 -> packed bf16
    uint r;
    asm("v_cvt_pk_bf16_f32 %0, %1, %2" : "=v"(r) : "v"(lo), "v"(hi));
    return r;
}

#define GLOAD16(gp, lp) __builtin_amdgcn_global_load_lds( \
    (__attribute__((address_space(1))) const void*)(gp),  \
    (__attribute__((address_space(3))) void*)(lp), 16, 0, 0)

// ---------------------------------------------------------------------------
// 1) fp32 -> bf16 convert: x and the four weight matrices (fused into wb)
// ---------------------------------------------------------------------------
__global__ __launch_bounds__(256) void convert_all(
    const float* __restrict__ x,
    const float* __restrict__ wq, const float* __restrict__ wk,
    const float* __restrict__ wv, const float* __restrict__ wo,
    ushort* __restrict__ xb, ushort* __restrict__ wb)
{
    const size_t NX4 = (size_t)S_LEN * DIM / 4;   // 1,032,192
    const size_t NW4 = (size_t)DIM * DIM / 4;     //   589,824
    size_t i = (size_t)blockIdx.x * 256 + threadIdx.x;
    const float* src; ushort* dst;
    if (i < NX4)            { src = x;  dst = xb; }
    else if (i < NX4+1*NW4) { src = wq; dst = wb;                        i -= NX4; }
    else if (i < NX4+2*NW4) { src = wk; dst = wb + 1*(size_t)DIM*DIM;    i -= NX4+1*NW4; }
    else if (i < NX4+3*NW4) { src = wv; dst = wb + 2*(size_t)DIM*DIM;    i -= NX4+2*NW4; }
    else if (i < NX4+4*NW4) { src = wo; dst = wb + 3*(size_t)DIM*DIM;    i -= NX4+3*NW4; }
    else return;
    float4 v = reinterpret_cast<const float4*>(src)[i];
    ushort4 o = { f2bf(v.x), f2bf(v.y), f2bf(v.z), f2bf(v.w) };
    reinterpret_cast<ushort4*>(dst)[i] = o;
}

// ---------------------------------------------------------------------------
// 2) QKV GEMM, bf16 out: q/k -> qkb [S][3072]; V -> v_t [d][S] transposed.
//    128x128 tile, BK=64, 4 waves (2x2), 16x16x32 MFMA, global_load_lds w=16.
// ---------------------------------------------------------------------------
__global__ __launch_bounds__(256) void gemm_qkv(
    const ushort* __restrict__ A, const ushort* __restrict__ B,
    const float* __restrict__ bq, const float* __restrict__ bk,
    const float* __restrict__ bv,
    ushort* __restrict__ qkb, ushort* __restrict__ v_t, int K)
{
    __shared__ ushort At[128 * 64];
    __shared__ ushort Bt[128 * 64];
    const int tid  = threadIdx.x;
    const int wave = tid >> 6, lane = tid & 63;
    const int m0 = blockIdx.x * 128, n0 = blockIdx.y * 128;
    const int wr = wave >> 1, wc = wave & 1;
    const int r = lane & 15, g = lane >> 4;
    const int srow = wave * 8 + (lane >> 3);
    const int scol = (lane & 7) * 8;

    f32x4 acc[4][4] = {};

    for (int k0 = 0; k0 < K; k0 += 64) {
        const ushort* Ag = A + (size_t)m0 * K + k0;
        const ushort* Bg = B + (size_t)n0 * K + k0;
#pragma unroll
        for (int t = 0; t < 4; ++t) {
            GLOAD16(Ag + (size_t)(t*32 + srow) * K + scol, &At[t*2048 + wave*512]);
            GLOAD16(Bg + (size_t)(t*32 + srow) * K + scol, &Bt[t*2048 + wave*512]);
        }
        asm volatile("s_waitcnt vmcnt(0)" ::: "memory");
        __syncthreads();
#pragma unroll
        for (int kk = 0; kk < 2; ++kk) {
            bf16x8 af[4], bfr[4];
#pragma unroll
            for (int i = 0; i < 4; ++i)
                af[i] = *reinterpret_cast<const bf16x8*>(
                    &At[(wr*64 + i*16 + r) * 64 + kk*32 + g*8]);
#pragma unroll
            for (int i = 0; i < 4; ++i)
                bfr[i] = *reinterpret_cast<const bf16x8*>(
                    &Bt[(wc*64 + i*16 + r) * 64 + kk*32 + g*8]);
#pragma unroll
            for (int mi = 0; mi < 4; ++mi)
#pragma unroll
                for (int ni = 0; ni < 4; ++ni)
                    acc[mi][ni] = __builtin_amdgcn_mfma_f32_16x16x32_bf16(
                        af[mi], bfr[ni], acc[mi][ni], 0, 0, 0);
        }
        __syncthreads();
    }

    if (n0 < 2*DIM) {       // q/k region (block-uniform branch)
#pragma unroll
        for (int ni = 0; ni < 4; ++ni) {
            int col = n0 + wc*64 + ni*16 + r;
            float bias = (col < DIM) ? bq[col] : bk[col - DIM];
#pragma unroll
            for (int mi = 0; mi < 4; ++mi) {
                int row = m0 + wr*64 + mi*16 + g*4;
#pragma unroll
                for (int j = 0; j < 4; ++j)
                    qkb[(size_t)(row + j) * (2*DIM) + col] =
                        f2bf(acc[mi][ni][j] + bias);
            }
        }
    } else {                // V region: transposed 8B stores into v_t[d][s]
#pragma unroll
        for (int ni = 0; ni < 4; ++ni) {
            int d = n0 - 2*DIM + wc*64 + ni*16 + r;
            float bias = bv[d];
#pragma unroll
            for (int mi = 0; mi < 4; ++mi) {
                int row = m0 + wr*64 + mi*16 + g*4;
                uint2 pkt;
                pkt.x = cvtpk(acc[mi][ni][0] + bias, acc[mi][ni][1] + bias);
                pkt.y = cvtpk(acc[mi][ni][2] + bias, acc[mi][ni][3] + bias);
                *reinterpret_cast<uint2*>(&v_t[(size_t)d * S_LEN + row]) = pkt;
            }
        }
    }
}

// ---------------------------------------------------------------------------
// 2b) bf16 GEMM for the out-projection: BM=128, BN=64 -> 504 blocks (2/CU).
// ---------------------------------------------------------------------------
__global__ __launch_bounds__(256) void gemm_bt2(
    const ushort* __restrict__ A, const ushort* __restrict__ B,
    const float* __restrict__ b0,
    float* __restrict__ C, int M, int N, int K)
{
    __shared__ ushort At[128 * 64];   // 16 KB
    __shared__ ushort Bt[64 * 64];    //  8 KB
    const int tid  = threadIdx.x;
    const int wave = tid >> 6, lane = tid & 63;
    const int m0 = blockIdx.x * 128, n0 = blockIdx.y * 64;
    const int wr = wave >> 1, wc = wave & 1;
    const int r = lane & 15, g = lane >> 4;
    const int srow = wave * 8 + (lane >> 3);
    const int scol = (lane & 7) * 8;
    const int brow[2] = { (0*256+tid)>>3, (1*256+tid)>>3 };
    const int bcol = (tid & 7) * 8;

    f32x4 acc[4][2] = {};

    for (int k0 = 0; k0 < K; k0 += 64) {
        const ushort* Ag = A + (size_t)m0 * K + k0;
        const ushort* Bg = B + (size_t)n0 * K + k0;
#pragma unroll
        for (int t = 0; t < 4; ++t)
            GLOAD16(Ag + (size_t)(t*32 + srow) * K + scol, &At[t*2048 + wave*512]);
#pragma unroll
        for (int t = 0; t < 2; ++t)
            GLOAD16(Bg + (size_t)brow[t] * K + bcol, &Bt[(t*256 + wave*64) * 8]);
        asm volatile("s_waitcnt vmcnt(0)" ::: "memory");
        __syncthreads();
#pragma unroll
        for (int kk = 0; kk < 2; ++kk) {
            bf16x8 af[4], bfr[2];
#pragma unroll
            for (int i = 0; i < 4; ++i)
                af[i] = *reinterpret_cast<const bf16x8*>(
                    &At[(wr*64 + i*16 + r) * 64 + kk*32 + g*8]);
#pragma unroll
            for (int i = 0; i < 2; ++i)
                bfr[i] = *reinterpret_cast<const bf16x8*>(
                    &Bt[(wc*32 + i*16 + r) * 64 + kk*32 + g*8]);
#pragma unroll
            for (int mi = 0; mi < 4; ++mi)
#pragma unroll
                for (int ni = 0; ni < 2; ++ni)
                    acc[mi][ni] = __builtin_amdgcn_mfma_f32_16x16x32_bf16(
                        af[mi], bfr[ni], acc[mi][ni], 0, 0, 0);
        }
        __syncthreads();
    }

#pragma unroll
    for (int ni = 0; ni < 2; ++ni) {
        int col = n0 + wc*32 + ni*16 + r;
        float bias = b0[col];
#pragma unroll
        for (int mi = 0; mi < 4; ++mi) {
            int row = m0 + wr*64 + mi*16 + g*4;
#pragma unroll
            for (int j = 0; j < 4; ++j)
                C[(size_t)(row + j) * N + col] = acc[mi][ni][j] + bias;
        }
    }
}

// ---------------------------------------------------------------------------
// 3) RMS-norm + RoPE for q,k from bf16 qkb; writes head-major bf16 [n][s][d].
//    1/sqrt(D)*log2(e) folded into q (exp2-domain softmax downstream).
// ---------------------------------------------------------------------------
__global__ __launch_bounds__(256) void normrope(
    const ushort* __restrict__ qkb, const int* __restrict__ gsz,
    const float* __restrict__ gq, const float* __restrict__ gk,
    const float* __restrict__ fcos, const float* __restrict__ fsin,
    ushort* __restrict__ q_r, ushort* __restrict__ k_r)
{
    const int s   = blockIdx.x;
    const int tid = threadIdx.x;
    const int wave = tid >> 6, lane = tid & 63;
    const uint* qrow = reinterpret_cast<const uint*>(qkb + (size_t)s * (2*DIM));
    const uint* krow = qrow + DIM/2;   // 768 uints = 1536 bf16

    float2 qv[3], kv[3];
    float sq = 0.f, sk = 0.f;
#pragma unroll
    for (int i = 0; i < 3; ++i) {
        int p = tid + i*256;
        uint uq = qrow[p], uk = krow[p];
        qv[i].x = bf2f(uq & 0xffffu); qv[i].y = bf2f(uq >> 16);
        kv[i].x = bf2f(uk & 0xffffu); kv[i].y = bf2f(uk >> 16);
        sq += qv[i].x*qv[i].x + qv[i].y*qv[i].y;
        sk += kv[i].x*kv[i].x + kv[i].y*kv[i].y;
    }
#pragma unroll
    for (int off = 1; off < 64; off <<= 1) {
        sq += __shfl_xor(sq, off);
        sk += __shfl_xor(sk, off);
    }
    __shared__ float red[4][2];
    if (lane == 0) { red[wave][0] = sq; red[wave][1] = sk; }
    __syncthreads();
    sq = red[0][0] + red[1][0] + red[2][0] + red[3][0];
    sk = red[0][1] + red[1][1] + red[2][1] + red[3][1];
    const float rmsq = rsqrtf(sq * (1.f/DIM) + 1e-6f);
    const float rmsk = rsqrtf(sk * (1.f/DIM) + 1e-6f);

    const int hh = gsz[1], ww = gsz[2];
    const int fidx = s / (hh*ww), rem = s % (hh*ww);
    const int hidx = rem / ww,  widx = rem % ww;
    // fold 1/sqrt(128) * log2(e): softmax runs in exp2 domain
    const float qscale = rmsq * (0.08838834764831845f * 1.4426950408889634f);

#pragma unroll
    for (int i = 0; i < 3; ++i) {
        int p = tid + i*256;               // pair index 0..767
        int c = p & 63, head = p >> 6;
        int coord = (c < 22) ? fidx : (c < 43) ? hidx : widx;
        float cv = fcos[coord*64 + c], sv = fsin[coord*64 + c];
        float2 gqv = reinterpret_cast<const float2*>(gq)[p];
        float2 gkv = reinterpret_cast<const float2*>(gk)[p];
        float a = qv[i].x * qscale * gqv.x, b = qv[i].y * qscale * gqv.y;
        uint qo = cvtpk(a*cv - b*sv, a*sv + b*cv);
        a = kv[i].x * rmsk * gkv.x; b = kv[i].y * rmsk * gkv.y;
        uint ko = cvtpk(a*cv - b*sv, a*sv + b*cv);
        size_t off = (((size_t)head * S_LEN + s) * HD + 2*c) >> 1;  // uint idx
        reinterpret_cast<uint*>(q_r)[off] = qo;
        reinterpret_cast<uint*>(k_r)[off] = ko;
    }
}

// ---------------------------------------------------------------------------
// 5) Flash attention: K LDS-staged (dbuf, XOR chunk swizzle); V in REGISTERS,
//    double-buffered ONE ITERATION AHEAD (vA=even tiles, vB=odd) — prefetch
//    issued alongside the next tile's K-DMA and drained by the same
//    vmcnt(0)+barrier, so V's L3 latency hides under a full iteration of
//    compute (fixes R10's same-iteration exposure; mapping HW-verified R10).
//    Swapped-operand QK^T/PV, in-lane softmax, defer-max THR=8 (exp2 domain,
//    raw v_exp_f32), P via cvt_pk -> per-wave LDS buffer.
// ---------------------------------------------------------------------------
__global__ __launch_bounds__(256) void attn_fwd(
    const ushort* __restrict__ q_r, const ushort* __restrict__ k_r,
    const ushort* __restrict__ v_t, const int* __restrict__ seq_lens,
    ushort* __restrict__ attn_out)
{
    __shared__ ushort Kl[2][64 * 128];   // 2 x 16 KB
    __shared__ ushort Pl[4][16 * 72];    // per-wave P, stride 72
    const int tid  = threadIdx.x;
    const int wave = tid >> 6, lane = tid & 63;
    const int n  = blockIdx.y;
    const int q0 = blockIdx.x * 64 + wave * 16;
    const int seq = seq_lens[0];
    const int r = lane & 15, g = lane >> 4;
    const int swz = r & 7;
    const ushort* Qh = q_r + (size_t)n * S_LEN * HD;
    const ushort* Kh = k_r + (size_t)n * S_LEN * HD;
    const ushort* Vh = v_t + (size_t)n * HD * S_LEN;

    const int kj_row[4] = { (0*256+tid)>>4, (1*256+tid)>>4, (2*256+tid)>>4, (3*256+tid)>>4 };
    const int kj_w  = tid & 15;
    // V direct-load base: lane reads V[db*16+r][kbase + kb2*32 + g*8 ..+7]
    const ushort* Vbase = Vh + (size_t)r * S_LEN + g*8;

    bf16x8 qf[4];
#pragma unroll
    for (int c = 0; c < 4; ++c)
        qf[c] = *reinterpret_cast<const bf16x8*>(Qh + (size_t)(q0 + r) * HD + c*32 + g*8);

    f32x4 oacc[8] = {};
    float mrun = -1e30f, lrun = 0.f;
    bf16x8 vA[8][2], vB[8][2];   // named sets (rule #20: no runtime indexing)

    const int nt = (seq + 63) >> 6;

#define STAGE_K(buf, kbase)                                                   \
    do {                                                                      \
        _Pragma("unroll")                                                     \
        for (int t = 0; t < 4; ++t) {                                         \
            int row = kj_row[t];                                              \
            GLOAD16(Kh + (size_t)((kbase) + row) * HD + ((kj_w ^ (row & 7)) * 8), \
                    &Kl[buf][(t*256 + wave*64) * 8]);                         \
        }                                                                     \
    } while (0)

#define PREFETCH_V(VR, kbase)                                                 \
    do {                                                                      \
        _Pragma("unroll")                                                     \
        for (int db = 0; db < 8; ++db)                                        \
            _Pragma("unroll")                                                 \
            for (int kb2 = 0; kb2 < 2; ++kb2)                                 \
                VR[db][kb2] = *reinterpret_cast<const bf16x8*>(               \
                    Vbase + (size_t)(db*16) * S_LEN + (kbase) + kb2*32);      \
    } while (0)

    auto compute = [&](int k0c, const ushort* KL, bf16x8 (&VR)[8][2]) {
        // ---- QK^T swapped: sf[kb][j] = S[key=k0c+kb*16+g*4+j][q=r]
        f32x4 sf[4];
#pragma unroll
        for (int kb = 0; kb < 4; ++kb) {
            f32x4 s = {0.f, 0.f, 0.f, 0.f};
            const ushort* kl = KL + (kb*16 + r) * 128;
#pragma unroll
            for (int c = 0; c < 4; ++c)
                s = __builtin_amdgcn_mfma_f32_16x16x32_bf16(
                    *reinterpret_cast<const bf16x8*>(kl + ((4*c + g) ^ swz) * 8),
                    qf[c], s, 0, 0, 0);
            sf[kb] = s;
        }
        if (k0c + 64 > seq) {   // tail mask (safety; S=2688 divisible by 64)
#pragma unroll
            for (int kb = 0; kb < 4; ++kb)
#pragma unroll
                for (int j = 0; j < 4; ++j)
                    if (k0c + kb*16 + g*4 + j >= seq) sf[kb][j] = -1e30f;
        }
        // ---- in-lane row max + 2 shfl
        float pm = fmaxf(fmaxf(fmaxf(sf[0][0], sf[0][1]), fmaxf(sf[0][2], sf[0][3])),
                         fmaxf(fmaxf(sf[1][0], sf[1][1]), fmaxf(sf[1][2], sf[1][3])));
        pm = fmaxf(pm, fmaxf(fmaxf(fmaxf(sf[2][0], sf[2][1]), fmaxf(sf[2][2], sf[2][3])),
                             fmaxf(fmaxf(sf[3][0], sf[3][1]), fmaxf(sf[3][2], sf[3][3]))));
        pm = fmaxf(pm, __shfl_xor(pm, 16));
        pm = fmaxf(pm, __shfl_xor(pm, 32));
        // ---- defer-max (THR=8, log2 domain)
        if (!__all(pm - mrun <= 8.f)) {
            float mn = fmaxf(mrun, pm);
            float scl = fexp2(mrun - mn);
            mrun = mn;
            lrun *= scl;
#pragma unroll
            for (int f = 0; f < 8; ++f)
#pragma unroll
                for (int j = 0; j < 4; ++j) oacc[f][j] *= scl;
        }
        // ---- P = exp2(S - mrun), in-lane sum + 2 shfl
        float ps = 0.f;
#pragma unroll
        for (int kb = 0; kb < 4; ++kb) {
            float e0 = fexp2(sf[kb][0] - mrun), e1 = fexp2(sf[kb][1] - mrun);
            float e2 = fexp2(sf[kb][2] - mrun), e3 = fexp2(sf[kb][3] - mrun);
            sf[kb][0] = e0; sf[kb][1] = e1; sf[kb][2] = e2; sf[kb][3] = e3;
            ps += (e0 + e1) + (e2 + e3);
        }
        ps += __shfl_xor(ps, 16);
        ps += __shfl_xor(ps, 32);
        lrun += ps;
        // ---- P -> LDS via cvt_pk (one b64 write per kb)
#pragma unroll
        for (int kb = 0; kb < 4; ++kb) {
            uint2 pkt;
            pkt.x = cvtpk(sf[kb][0], sf[kb][1]);
            pkt.y = cvtpk(sf[kb][2], sf[kb][3]);
            *reinterpret_cast<uint2*>(&Pl[wave][r*72 + kb*16 + g*4]) = pkt;
        }
        bf16x8 pf[2];
        pf[0] = *reinterpret_cast<const bf16x8*>(&Pl[wave][r*72 + g*8]);
        pf[1] = *reinterpret_cast<const bf16x8*>(&Pl[wave][r*72 + 32 + g*8]);
        // ---- PV swapped: oacc[db] += mfma(V_regfrag, P_frag) -> O[d][q]
#pragma unroll
        for (int db = 0; db < 8; ++db)
#pragma unroll
            for (int kb2 = 0; kb2 < 2; ++kb2)
                oacc[db] = __builtin_amdgcn_mfma_f32_16x16x32_bf16(
                    VR[db][kb2], pf[kb2], oacc[db], 0, 0, 0);
    };

    STAGE_K(0, 0);
    PREFETCH_V(vA, 0);
    asm volatile("s_waitcnt vmcnt(0)" ::: "memory");
    __syncthreads();

    for (int kt = 0; kt < nt; kt += 2) {
        const bool hasB = (kt + 1 < nt);
        if (hasB) { STAGE_K(1, (kt+1)*64); PREFETCH_V(vB, (kt+1)*64); }
        compute(kt*64, &Kl[0][0], vA);
        if (hasB) {
            asm volatile("s_waitcnt vmcnt(0)" ::: "memory");
            __syncthreads();
            const bool hasC = (kt + 2 < nt);
            if (hasC) { STAGE_K(0, (kt+2)*64); PREFETCH_V(vA, (kt+2)*64); }
            compute((kt+1)*64, &Kl[1][0], vB);
            if (hasC) {
                asm volatile("s_waitcnt vmcnt(0)" ::: "memory");
                __syncthreads();
            }
        }
    }
#undef STAGE_K
#undef PREFETCH_V

    const float inv = (lrun > 0.f) ? 1.f / lrun : 0.f;
#pragma unroll
    for (int db = 0; db < 8; ++db) {
        uint2 pkt;
        pkt.x = cvtpk(oacc[db][0]*inv, oacc[db][1]*inv);
        pkt.y = cvtpk(oacc[db][2]*inv, oacc[db][3]*inv);
        *reinterpret_cast<uint2*>(
            &attn_out[(size_t)(q0 + r) * DIM + n*HD + db*16 + g*4]) = pkt;
    }
}

// ---------------------------------------------------------------------------
extern "C" void kernel_launch(void* const* d_in, const int* in_sizes, int n_in,
                              void* d_out, int out_size, void* d_ws, size_t ws_size,
                              hipStream_t stream)
{
    const float* x    = (const float*)d_in[0];
    const int*   seqL = (const int*)  d_in[1];
    const int*   gsz  = (const int*)  d_in[2];
    const float* fcos = (const float*)d_in[3];
    const float* fsin = (const float*)d_in[4];
    const float* Wq   = (const float*)d_in[5];
    const float* bq   = (const float*)d_in[6];
    const float* Wk   = (const float*)d_in[7];
    const float* bk   = (const float*)d_in[8];
    const float* Wv   = (const float*)d_in[9];
    const float* bv   = (const float*)d_in[10];
    const float* Wo   = (const float*)d_in[11];
    const float* bo   = (const float*)d_in[12];
    const float* gq   = (const float*)d_in[13];
    const float* gk   = (const float*)d_in[14];
    float* out = (float*)d_out;

    char* ws = (char*)d_ws;
    ushort* xb  = (ushort*)ws;                     // S*DIM         =  8.26 MB
    ushort* wb  = xb  + (size_t)S_LEN * DIM;       // 4*DIM*DIM     = 18.87 MB
    ushort* qkb = wb  + 4*(size_t)DIM*DIM;         // S*3072        = 16.52 MB
    ushort* v_t = qkb + (size_t)S_LEN * 2*DIM;     // DIM*S         =  8.26 MB
    ushort* q_r = v_t + (size_t)DIM * S_LEN;       // S*DIM         =  8.26 MB
    ushort* k_r = q_r + (size_t)S_LEN * DIM;       // S*DIM         =  8.26 MB
    ushort* ao  = k_r + (size_t)S_LEN * DIM;       // S*DIM         =  8.26 MB
    // total ws use: ~76.7 MB

    convert_all<<<13248, 256, 0, stream>>>(x, Wq, Wk, Wv, Wo, xb, wb);
    gemm_qkv<<<dim3(21, 36), 256, 0, stream>>>(xb, wb, bq, bk, bv,
                                               qkb, v_t, DIM);
    normrope<<<S_LEN, 256, 0, stream>>>(qkb, gsz, gq, gk, fcos, fsin, q_r, k_r);
    attn_fwd<<<dim3(42, 12), 256, 0, stream>>>(q_r, k_r, v_t, seqL, ao);
    gemm_bt2<<<dim3(21, 24), 256, 0, stream>>>(ao, wb + 3*(size_t)DIM*DIM,
                                               bo, out, S_LEN, DIM, DIM);
}

// Round 13
// 216.935 us; speedup vs baseline: 1.6975x; 1.6975x over previous
//
#include <hip/hip_runtime.h>
#include <hip/hip_bf16.h>
#include <stdint.h>

#define S_LEN 2688
#define DIM   1536
#define NH    12
#define HD    128
#define QKV_N 4608   // 3*DIM

typedef __attribute__((ext_vector_type(8))) short bf16x8;
typedef __attribute__((ext_vector_type(4))) float f32x4;

__device__ inline ushort f2bf(float f) {
    uint32_t u = __float_as_uint(f);
    uint32_t r = (u + 0x7fffu + ((u >> 16) & 1u)) >> 16;
    return (ushort)r;
}
__device__ inline float bf2f(uint u) { return __uint_as_float(u << 16); }
__device__ inline float fexp2(float x) {           // raw v_exp_f32 (2^x); args
    float r;                                       // bounded by defer-max
    asm("v_exp_f32 %0, %1" : "=v"(r) : "v"(x));
    return r;
}
__device__ inline uint cvtpk(float lo, float hi) { // 2xf32 -> packed bf16
    uint r;
    asm("v_cvt_pk_bf16_f32 %0, %1, %2" : "=v"(r) : "v"(lo), "v"(hi));
    return r;
}

#define GLOAD16(gp, lp) __builtin_amdgcn_global_load_lds( \
    (__attribute__((address_space(1))) const void*)(gp),  \
    (__attribute__((address_space(3))) void*)(lp), 16, 0, 0)

// ---------------------------------------------------------------------------
// 1) fp32 -> bf16 convert: x and the four weight matrices (fused into wb)
// ---------------------------------------------------------------------------
__global__ __launch_bounds__(256) void convert_all(
    const float* __restrict__ x,
    const float* __restrict__ wq, const float* __restrict__ wk,
    const float* __restrict__ wv, const float* __restrict__ wo,
    ushort* __restrict__ xb, ushort* __restrict__ wb)
{
    const size_t NX4 = (size_t)S_LEN * DIM / 4;   // 1,032,192
    const size_t NW4 = (size_t)DIM * DIM / 4;     //   589,824
    size_t i = (size_t)blockIdx.x * 256 + threadIdx.x;
    const float* src; ushort* dst;
    if (i < NX4)            { src = x;  dst = xb; }
    else if (i < NX4+1*NW4) { src = wq; dst = wb;                        i -= NX4; }
    else if (i < NX4+2*NW4) { src = wk; dst = wb + 1*(size_t)DIM*DIM;    i -= NX4+1*NW4; }
    else if (i < NX4+3*NW4) { src = wv; dst = wb + 2*(size_t)DIM*DIM;    i -= NX4+2*NW4; }
    else if (i < NX4+4*NW4) { src = wo; dst = wb + 3*(size_t)DIM*DIM;    i -= NX4+3*NW4; }
    else return;
    float4 v = reinterpret_cast<const float4*>(src)[i];
    ushort4 o = { f2bf(v.x), f2bf(v.y), f2bf(v.z), f2bf(v.w) };
    reinterpret_cast<ushort4*>(dst)[i] = o;
}

// ---------------------------------------------------------------------------
// 2) QKV GEMM, bf16 out: q/k -> qkb [S][3072]; V -> v_t [d][S] transposed.
//    128x128 tile, BK=64, 4 waves (2x2), 16x16x32 MFMA, global_load_lds w=16.
//    XCD chunk-swizzle (T1, m204 bijective: nwg=756, q=94, r=4) so each
//    XCD's L2 sees contiguous runs of blocks sharing the same B-tile.
// ---------------------------------------------------------------------------
__global__ __launch_bounds__(256) void gemm_qkv(
    const ushort* __restrict__ A, const ushort* __restrict__ B,
    const float* __restrict__ bq, const float* __restrict__ bk,
    const float* __restrict__ bv,
    ushort* __restrict__ qkb, ushort* __restrict__ v_t, int K)
{
    __shared__ ushort At[128 * 64];
    __shared__ ushort Bt[128 * 64];
    const int tid  = threadIdx.x;
    const int wave = tid >> 6, lane = tid & 63;
    // m204 bijective XCD swizzle of the 756-block grid (x fastest)
    const int lid  = blockIdx.y * 21 + blockIdx.x;
    const int xcd  = lid & 7, pos = lid >> 3;
    const int wgid = (xcd < 4 ? xcd * 95 : 4 * 95 + (xcd - 4) * 94) + pos;
    const int m0 = (wgid % 21) * 128, n0 = (wgid / 21) * 128;
    const int wr = wave >> 1, wc = wave & 1;
    const int r = lane & 15, g = lane >> 4;
    const int srow = wave * 8 + (lane >> 3);
    const int scol = (lane & 7) * 8;

    f32x4 acc[4][4] = {};

    for (int k0 = 0; k0 < K; k0 += 64) {
        const ushort* Ag = A + (size_t)m0 * K + k0;
        const ushort* Bg = B + (size_t)n0 * K + k0;
#pragma unroll
        for (int t = 0; t < 4; ++t) {
            GLOAD16(Ag + (size_t)(t*32 + srow) * K + scol, &At[t*2048 + wave*512]);
            GLOAD16(Bg + (size_t)(t*32 + srow) * K + scol, &Bt[t*2048 + wave*512]);
        }
        asm volatile("s_waitcnt vmcnt(0)" ::: "memory");
        __syncthreads();
#pragma unroll
        for (int kk = 0; kk < 2; ++kk) {
            bf16x8 af[4], bfr[4];
#pragma unroll
            for (int i = 0; i < 4; ++i)
                af[i] = *reinterpret_cast<const bf16x8*>(
                    &At[(wr*64 + i*16 + r) * 64 + kk*32 + g*8]);
#pragma unroll
            for (int i = 0; i < 4; ++i)
                bfr[i] = *reinterpret_cast<const bf16x8*>(
                    &Bt[(wc*64 + i*16 + r) * 64 + kk*32 + g*8]);
#pragma unroll
            for (int mi = 0; mi < 4; ++mi)
#pragma unroll
                for (int ni = 0; ni < 4; ++ni)
                    acc[mi][ni] = __builtin_amdgcn_mfma_f32_16x16x32_bf16(
                        af[mi], bfr[ni], acc[mi][ni], 0, 0, 0);
        }
        __syncthreads();
    }

    if (n0 < 2*DIM) {       // q/k region (block-uniform branch)
#pragma unroll
        for (int ni = 0; ni < 4; ++ni) {
            int col = n0 + wc*64 + ni*16 + r;
            float bias = (col < DIM) ? bq[col] : bk[col - DIM];
#pragma unroll
            for (int mi = 0; mi < 4; ++mi) {
                int row = m0 + wr*64 + mi*16 + g*4;
#pragma unroll
                for (int j = 0; j < 4; ++j)
                    qkb[(size_t)(row + j) * (2*DIM) + col] =
                        f2bf(acc[mi][ni][j] + bias);
            }
        }
    } else {                // V region: transposed 8B stores into v_t[d][s]
#pragma unroll
        for (int ni = 0; ni < 4; ++ni) {
            int d = n0 - 2*DIM + wc*64 + ni*16 + r;
            float bias = bv[d];
#pragma unroll
            for (int mi = 0; mi < 4; ++mi) {
                int row = m0 + wr*64 + mi*16 + g*4;
                uint2 pkt;
                pkt.x = cvtpk(acc[mi][ni][0] + bias, acc[mi][ni][1] + bias);
                pkt.y = cvtpk(acc[mi][ni][2] + bias, acc[mi][ni][3] + bias);
                *reinterpret_cast<uint2*>(&v_t[(size_t)d * S_LEN + row]) = pkt;
            }
        }
    }
}

// ---------------------------------------------------------------------------
// 2b) bf16 GEMM for the out-projection: BM=128, BN=64 -> 504 blocks (2/CU).
// ---------------------------------------------------------------------------
__global__ __launch_bounds__(256) void gemm_bt2(
    const ushort* __restrict__ A, const ushort* __restrict__ B,
    const float* __restrict__ b0,
    float* __restrict__ C, int M, int N, int K)
{
    __shared__ ushort At[128 * 64];   // 16 KB
    __shared__ ushort Bt[64 * 64];    //  8 KB
    const int tid  = threadIdx.x;
    const int wave = tid >> 6, lane = tid & 63;
    const int m0 = blockIdx.x * 128, n0 = blockIdx.y * 64;
    const int wr = wave >> 1, wc = wave & 1;
    const int r = lane & 15, g = lane >> 4;
    const int srow = wave * 8 + (lane >> 3);
    const int scol = (lane & 7) * 8;
    const int brow[2] = { (0*256+tid)>>3, (1*256+tid)>>3 };
    const int bcol = (tid & 7) * 8;

    f32x4 acc[4][2] = {};

    for (int k0 = 0; k0 < K; k0 += 64) {
        const ushort* Ag = A + (size_t)m0 * K + k0;
        const ushort* Bg = B + (size_t)n0 * K + k0;
#pragma unroll
        for (int t = 0; t < 4; ++t)
            GLOAD16(Ag + (size_t)(t*32 + srow) * K + scol, &At[t*2048 + wave*512]);
#pragma unroll
        for (int t = 0; t < 2; ++t)
            GLOAD16(Bg + (size_t)brow[t] * K + bcol, &Bt[(t*256 + wave*64) * 8]);
        asm volatile("s_waitcnt vmcnt(0)" ::: "memory");
        __syncthreads();
#pragma unroll
        for (int kk = 0; kk < 2; ++kk) {
            bf16x8 af[4], bfr[2];
#pragma unroll
            for (int i = 0; i < 4; ++i)
                af[i] = *reinterpret_cast<const bf16x8*>(
                    &At[(wr*64 + i*16 + r) * 64 + kk*32 + g*8]);
#pragma unroll
            for (int i = 0; i < 2; ++i)
                bfr[i] = *reinterpret_cast<const bf16x8*>(
                    &Bt[(wc*32 + i*16 + r) * 64 + kk*32 + g*8]);
#pragma unroll
            for (int mi = 0; mi < 4; ++mi)
#pragma unroll
                for (int ni = 0; ni < 2; ++ni)
                    acc[mi][ni] = __builtin_amdgcn_mfma_f32_16x16x32_bf16(
                        af[mi], bfr[ni], acc[mi][ni], 0, 0, 0);
        }
        __syncthreads();
    }

#pragma unroll
    for (int ni = 0; ni < 2; ++ni) {
        int col = n0 + wc*32 + ni*16 + r;
        float bias = b0[col];
#pragma unroll
        for (int mi = 0; mi < 4; ++mi) {
            int row = m0 + wr*64 + mi*16 + g*4;
#pragma unroll
            for (int j = 0; j < 4; ++j)
                C[(size_t)(row + j) * N + col] = acc[mi][ni][j] + bias;
        }
    }
}

// ---------------------------------------------------------------------------
// 3) RMS-norm + RoPE for q,k from bf16 qkb; writes head-major bf16 [n][s][d].
//    1/sqrt(D)*log2(e) folded into q (exp2-domain softmax downstream).
// ---------------------------------------------------------------------------
__global__ __launch_bounds__(256) void normrope(
    const ushort* __restrict__ qkb, const int* __restrict__ gsz,
    const float* __restrict__ gq, const float* __restrict__ gk,
    const float* __restrict__ fcos, const float* __restrict__ fsin,
    ushort* __restrict__ q_r, ushort* __restrict__ k_r)
{
    const int s   = blockIdx.x;
    const int tid = threadIdx.x;
    const int wave = tid >> 6, lane = tid & 63;
    const uint* qrow = reinterpret_cast<const uint*>(qkb + (size_t)s * (2*DIM));
    const uint* krow = qrow + DIM/2;   // 768 uints = 1536 bf16

    float2 qv[3], kv[3];
    float sq = 0.f, sk = 0.f;
#pragma unroll
    for (int i = 0; i < 3; ++i) {
        int p = tid + i*256;
        uint uq = qrow[p], uk = krow[p];
        qv[i].x = bf2f(uq & 0xffffu); qv[i].y = bf2f(uq >> 16);
        kv[i].x = bf2f(uk & 0xffffu); kv[i].y = bf2f(uk >> 16);
        sq += qv[i].x*qv[i].x + qv[i].y*qv[i].y;
        sk += kv[i].x*kv[i].x + kv[i].y*kv[i].y;
    }
#pragma unroll
    for (int off = 1; off < 64; off <<= 1) {
        sq += __shfl_xor(sq, off);
        sk += __shfl_xor(sk, off);
    }
    __shared__ float red[4][2];
    if (lane == 0) { red[wave][0] = sq; red[wave][1] = sk; }
    __syncthreads();
    sq = red[0][0] + red[1][0] + red[2][0] + red[3][0];
    sk = red[0][1] + red[1][1] + red[2][1] + red[3][1];
    const float rmsq = rsqrtf(sq * (1.f/DIM) + 1e-6f);
    const float rmsk = rsqrtf(sk * (1.f/DIM) + 1e-6f);

    const int hh = gsz[1], ww = gsz[2];
    const int fidx = s / (hh*ww), rem = s % (hh*ww);
    const int hidx = rem / ww,  widx = rem % ww;
    // fold 1/sqrt(128) * log2(e): softmax runs in exp2 domain
    const float qscale = rmsq * (0.08838834764831845f * 1.4426950408889634f);

#pragma unroll
    for (int i = 0; i < 3; ++i) {
        int p = tid + i*256;               // pair index 0..767
        int c = p & 63, head = p >> 6;
        int coord = (c < 22) ? fidx : (c < 43) ? hidx : widx;
        float cv = fcos[coord*64 + c], sv = fsin[coord*64 + c];
        float2 gqv = reinterpret_cast<const float2*>(gq)[p];
        float2 gkv = reinterpret_cast<const float2*>(gk)[p];
        float a = qv[i].x * qscale * gqv.x, b = qv[i].y * qscale * gqv.y;
        uint qo = cvtpk(a*cv - b*sv, a*sv + b*cv);
        a = kv[i].x * rmsk * gkv.x; b = kv[i].y * rmsk * gkv.y;
        uint ko = cvtpk(a*cv - b*sv, a*sv + b*cv);
        size_t off = (((size_t)head * S_LEN + s) * HD + 2*c) >> 1;  // uint idx
        reinterpret_cast<uint*>(q_r)[off] = qo;
        reinterpret_cast<uint*>(k_r)[off] = ko;
    }
}

// ---------------------------------------------------------------------------
// 5) Flash attention (R9/R11-verified, 95 µs): K+V LDS-staged (dbuf, XOR
//    chunk swizzle), swapped-operand QK^T/PV, in-lane softmax, defer-max
//    THR=8 (exp2 domain, raw v_exp_f32), P via cvt_pk -> per-wave LDS.
//    NOTE: V-direct-to-reg attempted twice (R10 same-iter, R12 1-iter-ahead
//    dbuf) — both compiler-defeated (loads sunk to use site, latency
//    exposed, 2.5x regression). Do not retry without asm-level control.
// ---------------------------------------------------------------------------
__global__ __launch_bounds__(256) void attn_fwd(
    const ushort* __restrict__ q_r, const ushort* __restrict__ k_r,
    const ushort* __restrict__ v_t, const int* __restrict__ seq_lens,
    ushort* __restrict__ attn_out)
{
    __shared__ ushort Kl[2][64 * 128];   // 2 x 16 KB
    __shared__ ushort Vl[2][128 * 64];   // 2 x 16 KB
    __shared__ ushort Pl[4][16 * 72];    // per-wave P, stride 72
    const int tid  = threadIdx.x;
    const int wave = tid >> 6, lane = tid & 63;
    const int n  = blockIdx.y;
    const int q0 = blockIdx.x * 64 + wave * 16;
    const int seq = seq_lens[0];
    const int r = lane & 15, g = lane >> 4;
    const int swz = r & 7;
    const ushort* Qh = q_r + (size_t)n * S_LEN * HD;
    const ushort* Kh = k_r + (size_t)n * S_LEN * HD;
    const ushort* Vh = v_t + (size_t)n * HD * S_LEN;

    const int kj_row[4] = { (0*256+tid)>>4, (1*256+tid)>>4, (2*256+tid)>>4, (3*256+tid)>>4 };
    const int kj_w  = tid & 15;
    const int vj_d[4]  = { (0*256+tid)>>3, (1*256+tid)>>3, (2*256+tid)>>3, (3*256+tid)>>3 };
    const int vj_w  = tid & 7;

    bf16x8 qf[4];
#pragma unroll
    for (int c = 0; c < 4; ++c)
        qf[c] = *reinterpret_cast<const bf16x8*>(Qh + (size_t)(q0 + r) * HD + c*32 + g*8);

    f32x4 oacc[8] = {};
    float mrun = -1e30f, lrun = 0.f;

    const int nt = (seq + 63) >> 6;

#define STAGE(buf, kbase)                                                     \
    do {                                                                      \
        _Pragma("unroll")                                                     \
        for (int t = 0; t < 4; ++t) {                                         \
            int row = kj_row[t];                                              \
            GLOAD16(Kh + (size_t)((kbase) + row) * HD + ((kj_w ^ (row & 7)) * 8), \
                    &Kl[buf][(t*256 + wave*64) * 8]);                         \
        }                                                                     \
        _Pragma("unroll")                                                     \
        for (int t = 0; t < 4; ++t) {                                         \
            int d = vj_d[t];                                                  \
            GLOAD16(Vh + (size_t)d * S_LEN + (kbase) + ((vj_w ^ (d & 7)) * 8), \
                    &Vl[buf][(t*256 + wave*64) * 8]);                         \
        }                                                                     \
    } while (0)

    STAGE(0, 0);
    asm volatile("s_waitcnt vmcnt(0)" ::: "memory");
    __syncthreads();

    int cur = 0;
    for (int kt = 0; kt < nt; ++kt) {
        const int k0 = kt * 64;
        if (kt + 1 < nt) STAGE(cur ^ 1, k0 + 64);

        // ---- QK^T swapped: sf[kb][j] = S[key=k0+kb*16+g*4+j][q=r]
        f32x4 sf[4];
#pragma unroll
        for (int kb = 0; kb < 4; ++kb) {
            f32x4 s = {0.f, 0.f, 0.f, 0.f};
            const ushort* kl = &Kl[cur][(kb*16 + r) * 128];
#pragma unroll
            for (int c = 0; c < 4; ++c)
                s = __builtin_amdgcn_mfma_f32_16x16x32_bf16(
                    *reinterpret_cast<const bf16x8*>(kl + ((4*c + g) ^ swz) * 8),
                    qf[c], s, 0, 0, 0);
            sf[kb] = s;
        }
        if (k0 + 64 > seq) {   // tail mask (safety; S=2688 is divisible by 64)
#pragma unroll
            for (int kb = 0; kb < 4; ++kb)
#pragma unroll
                for (int j = 0; j < 4; ++j)
                    if (k0 + kb*16 + g*4 + j >= seq) sf[kb][j] = -1e30f;
        }
        // ---- in-lane row max + 2 shfl
        float pm = fmaxf(fmaxf(fmaxf(sf[0][0], sf[0][1]), fmaxf(sf[0][2], sf[0][3])),
                         fmaxf(fmaxf(sf[1][0], sf[1][1]), fmaxf(sf[1][2], sf[1][3])));
        pm = fmaxf(pm, fmaxf(fmaxf(fmaxf(sf[2][0], sf[2][1]), fmaxf(sf[2][2], sf[2][3])),
                             fmaxf(fmaxf(sf[3][0], sf[3][1]), fmaxf(sf[3][2], sf[3][3]))));
        pm = fmaxf(pm, __shfl_xor(pm, 16));
        pm = fmaxf(pm, __shfl_xor(pm, 32));
        // ---- defer-max (THR=8, log2 domain)
        if (!__all(pm - mrun <= 8.f)) {
            float mn = fmaxf(mrun, pm);
            float scl = fexp2(mrun - mn);
            mrun = mn;
            lrun *= scl;
#pragma unroll
            for (int f = 0; f < 8; ++f)
#pragma unroll
                for (int j = 0; j < 4; ++j) oacc[f][j] *= scl;
        }
        // ---- P = exp2(S - mrun), in-lane sum + 2 shfl
        float ps = 0.f;
#pragma unroll
        for (int kb = 0; kb < 4; ++kb) {
            float e0 = fexp2(sf[kb][0] - mrun), e1 = fexp2(sf[kb][1] - mrun);
            float e2 = fexp2(sf[kb][2] - mrun), e3 = fexp2(sf[kb][3] - mrun);
            sf[kb][0] = e0; sf[kb][1] = e1; sf[kb][2] = e2; sf[kb][3] = e3;
            ps += (e0 + e1) + (e2 + e3);
        }
        ps += __shfl_xor(ps, 16);
        ps += __shfl_xor(ps, 32);
        lrun += ps;
        // ---- P -> LDS via cvt_pk (one b64 write per kb)
#pragma unroll
        for (int kb = 0; kb < 4; ++kb) {
            uint2 pkt;
            pkt.x = cvtpk(sf[kb][0], sf[kb][1]);
            pkt.y = cvtpk(sf[kb][2], sf[kb][3]);
            *reinterpret_cast<uint2*>(&Pl[wave][r*72 + kb*16 + g*4]) = pkt;
        }
        bf16x8 pf[2];
        pf[0] = *reinterpret_cast<const bf16x8*>(&Pl[wave][r*72 + g*8]);
        pf[1] = *reinterpret_cast<const bf16x8*>(&Pl[wave][r*72 + 32 + g*8]);
        // ---- PV swapped: oacc[db] += mfma(V_frag, P_frag) -> O[d][q]
#pragma unroll
        for (int db = 0; db < 8; ++db) {
            const ushort* vl = &Vl[cur][(db*16 + r) * 64];
#pragma unroll
            for (int kb2 = 0; kb2 < 2; ++kb2)
                oacc[db] = __builtin_amdgcn_mfma_f32_16x16x32_bf16(
                    *reinterpret_cast<const bf16x8*>(vl + ((kb2*4 + g) ^ swz) * 8),
                    pf[kb2], oacc[db], 0, 0, 0);
        }

        if (kt + 1 < nt) {
            asm volatile("s_waitcnt vmcnt(0)" ::: "memory");
            __syncthreads();
            cur ^= 1;
        }
    }
#undef STAGE

    const float inv = (lrun > 0.f) ? 1.f / lrun : 0.f;
#pragma unroll
    for (int db = 0; db < 8; ++db) {
        uint2 pkt;
        pkt.x = cvtpk(oacc[db][0]*inv, oacc[db][1]*inv);
        pkt.y = cvtpk(oacc[db][2]*inv, oacc[db][3]*inv);
        *reinterpret_cast<uint2*>(
            &attn_out[(size_t)(q0 + r) * DIM + n*HD + db*16 + g*4]) = pkt;
    }
}

// ---------------------------------------------------------------------------
extern "C" void kernel_launch(void* const* d_in, const int* in_sizes, int n_in,
                              void* d_out, int out_size, void* d_ws, size_t ws_size,
                              hipStream_t stream)
{
    const float* x    = (const float*)d_in[0];
    const int*   seqL = (const int*)  d_in[1];
    const int*   gsz  = (const int*)  d_in[2];
    const float* fcos = (const float*)d_in[3];
    const float* fsin = (const float*)d_in[4];
    const float* Wq   = (const float*)d_in[5];
    const float* bq   = (const float*)d_in[6];
    const float* Wk   = (const float*)d_in[7];
    const float* bk   = (const float*)d_in[8];
    const float* Wv   = (const float*)d_in[9];
    const float* bv   = (const float*)d_in[10];
    const float* Wo   = (const float*)d_in[11];
    const float* bo   = (const float*)d_in[12];
    const float* gq   = (const float*)d_in[13];
    const float* gk   = (const float*)d_in[14];
    float* out = (float*)d_out;

    char* ws = (char*)d_ws;
    ushort* xb  = (ushort*)ws;                     // S*DIM         =  8.26 MB
    ushort* wb  = xb  + (size_t)S_LEN * DIM;       // 4*DIM*DIM     = 18.87 MB
    ushort* qkb = wb  + 4*(size_t)DIM*DIM;         // S*3072        = 16.52 MB
    ushort* v_t = qkb + (size_t)S_LEN * 2*DIM;     // DIM*S         =  8.26 MB
    ushort* q_r = v_t + (size_t)DIM * S_LEN;       // S*DIM         =  8.26 MB
    ushort* k_r = q_r + (size_t)S_LEN * DIM;       // S*DIM         =  8.26 MB
    ushort* ao  = k_r + (size_t)S_LEN * DIM;       // S*DIM         =  8.26 MB
    // total ws use: ~76.7 MB

    convert_all<<<13248, 256, 0, stream>>>(x, Wq, Wk, Wv, Wo, xb, wb);
    gemm_qkv<<<dim3(21, 36), 256, 0, stream>>>(xb, wb, bq, bk, bv,
                                               qkb, v_t, DIM);
    normrope<<<S_LEN, 256, 0, stream>>>(qkb, gsz, gq, gk, fcos, fsin, q_r, k_r);
    attn_fwd<<<dim3(42, 12), 256, 0, stream>>>(q_r, k_r, v_t, seqL, ao);
    gemm_bt2<<<dim3(21, 24), 256, 0, stream>>>(ao, wb + 3*(size_t)DIM*DIM,
                                               bo, out, S_LEN, DIM, DIM);
}

// Round 14
// 208.753 us; speedup vs baseline: 1.7640x; 1.0392x over previous
//
#include <hip/hip_runtime.h>
#include <hip/hip_bf16.h>
#include <stdint.h>

#define S_LEN 2688
#define DIM   1536
#define NH    12
#define HD    128
#define QKV_N 4608   // 3*DIM

typedef __attribute__((ext_vector_type(8)))  short bf16x8;
typedef __attribute__((ext_vector_type(4)))  float f32x4;
typedef __attribute__((ext_vector_type(16))) float f32x16;

__device__ inline ushort f2bf(float f) {
    uint32_t u = __float_as_uint(f);
    uint32_t r = (u + 0x7fffu + ((u >> 16) & 1u)) >> 16;
    return (ushort)r;
}
__device__ inline float bf2f(uint u) { return __uint_as_float(u << 16); }
__device__ inline float fexp2(float x) {           // raw v_exp_f32 (2^x); args
    float r;                                       // bounded by defer-max
    asm("v_exp_f32 %0, %1" : "=v"(r) : "v"(x));
    return r;
}
__device__ inline uint cvtpk(float lo, float hi) { // 2xf32 -> packed bf16
    uint r;
    asm("v_cvt_pk_bf16_f32 %0, %1, %2" : "=v"(r) : "v"(lo), "v"(hi));
    return r;
}

#define GLOAD16(gp, lp) __builtin_amdgcn_global_load_lds( \
    (__attribute__((address_space(1))) const void*)(gp),  \
    (__attribute__((address_space(3))) void*)(lp), 16, 0, 0)

// ---------------------------------------------------------------------------
// 1) fp32 -> bf16 convert: x and the four weight matrices (fused into wb)
// ---------------------------------------------------------------------------
__global__ __launch_bounds__(256) void convert_all(
    const float* __restrict__ x,
    const float* __restrict__ wq, const float* __restrict__ wk,
    const float* __restrict__ wv, const float* __restrict__ wo,
    ushort* __restrict__ xb, ushort* __restrict__ wb)
{
    const size_t NX4 = (size_t)S_LEN * DIM / 4;   // 1,032,192
    const size_t NW4 = (size_t)DIM * DIM / 4;     //   589,824
    size_t i = (size_t)blockIdx.x * 256 + threadIdx.x;
    const float* src; ushort* dst;
    if (i < NX4)            { src = x;  dst = xb; }
    else if (i < NX4+1*NW4) { src = wq; dst = wb;                        i -= NX4; }
    else if (i < NX4+2*NW4) { src = wk; dst = wb + 1*(size_t)DIM*DIM;    i -= NX4+1*NW4; }
    else if (i < NX4+3*NW4) { src = wv; dst = wb + 2*(size_t)DIM*DIM;    i -= NX4+2*NW4; }
    else if (i < NX4+4*NW4) { src = wo; dst = wb + 3*(size_t)DIM*DIM;    i -= NX4+3*NW4; }
    else return;
    float4 v = reinterpret_cast<const float4*>(src)[i];
    ushort4 o = { f2bf(v.x), f2bf(v.y), f2bf(v.z), f2bf(v.w) };
    reinterpret_cast<ushort4*>(dst)[i] = o;
}

// ---------------------------------------------------------------------------
// 2) QKV GEMM, bf16 out: q/k -> qkb [S][3072]; V -> v_t [d][S] transposed.
//    128x128 tile, BK=64, 4 waves (2x2), 16x16x32 MFMA, global_load_lds w=16.
//    XCD chunk-swizzle (T1, m204 bijective: nwg=756, q=94, r=4).
// ---------------------------------------------------------------------------
__global__ __launch_bounds__(256) void gemm_qkv(
    const ushort* __restrict__ A, const ushort* __restrict__ B,
    const float* __restrict__ bq, const float* __restrict__ bk,
    const float* __restrict__ bv,
    ushort* __restrict__ qkb, ushort* __restrict__ v_t, int K)
{
    __shared__ ushort At[128 * 64];
    __shared__ ushort Bt[128 * 64];
    const int tid  = threadIdx.x;
    const int wave = tid >> 6, lane = tid & 63;
    // m204 bijective XCD swizzle of the 756-block grid (x fastest)
    const int lid  = blockIdx.y * 21 + blockIdx.x;
    const int xcd  = lid & 7, pos = lid >> 3;
    const int wgid = (xcd < 4 ? xcd * 95 : 4 * 95 + (xcd - 4) * 94) + pos;
    const int m0 = (wgid % 21) * 128, n0 = (wgid / 21) * 128;
    const int wr = wave >> 1, wc = wave & 1;
    const int r = lane & 15, g = lane >> 4;
    const int srow = wave * 8 + (lane >> 3);
    const int scol = (lane & 7) * 8;

    f32x4 acc[4][4] = {};

    for (int k0 = 0; k0 < K; k0 += 64) {
        const ushort* Ag = A + (size_t)m0 * K + k0;
        const ushort* Bg = B + (size_t)n0 * K + k0;
#pragma unroll
        for (int t = 0; t < 4; ++t) {
            GLOAD16(Ag + (size_t)(t*32 + srow) * K + scol, &At[t*2048 + wave*512]);
            GLOAD16(Bg + (size_t)(t*32 + srow) * K + scol, &Bt[t*2048 + wave*512]);
        }
        asm volatile("s_waitcnt vmcnt(0)" ::: "memory");
        __syncthreads();
#pragma unroll
        for (int kk = 0; kk < 2; ++kk) {
            bf16x8 af[4], bfr[4];
#pragma unroll
            for (int i = 0; i < 4; ++i)
                af[i] = *reinterpret_cast<const bf16x8*>(
                    &At[(wr*64 + i*16 + r) * 64 + kk*32 + g*8]);
#pragma unroll
            for (int i = 0; i < 4; ++i)
                bfr[i] = *reinterpret_cast<const bf16x8*>(
                    &Bt[(wc*64 + i*16 + r) * 64 + kk*32 + g*8]);
#pragma unroll
            for (int mi = 0; mi < 4; ++mi)
#pragma unroll
                for (int ni = 0; ni < 4; ++ni)
                    acc[mi][ni] = __builtin_amdgcn_mfma_f32_16x16x32_bf16(
                        af[mi], bfr[ni], acc[mi][ni], 0, 0, 0);
        }
        __syncthreads();
    }

    if (n0 < 2*DIM) {       // q/k region (block-uniform branch)
#pragma unroll
        for (int ni = 0; ni < 4; ++ni) {
            int col = n0 + wc*64 + ni*16 + r;
            float bias = (col < DIM) ? bq[col] : bk[col - DIM];
#pragma unroll
            for (int mi = 0; mi < 4; ++mi) {
                int row = m0 + wr*64 + mi*16 + g*4;
#pragma unroll
                for (int j = 0; j < 4; ++j)
                    qkb[(size_t)(row + j) * (2*DIM) + col] =
                        f2bf(acc[mi][ni][j] + bias);
            }
        }
    } else {                // V region: transposed 8B stores into v_t[d][s]
#pragma unroll
        for (int ni = 0; ni < 4; ++ni) {
            int d = n0 - 2*DIM + wc*64 + ni*16 + r;
            float bias = bv[d];
#pragma unroll
            for (int mi = 0; mi < 4; ++mi) {
                int row = m0 + wr*64 + mi*16 + g*4;
                uint2 pkt;
                pkt.x = cvtpk(acc[mi][ni][0] + bias, acc[mi][ni][1] + bias);
                pkt.y = cvtpk(acc[mi][ni][2] + bias, acc[mi][ni][3] + bias);
                *reinterpret_cast<uint2*>(&v_t[(size_t)d * S_LEN + row]) = pkt;
            }
        }
    }
}

// ---------------------------------------------------------------------------
// 2b) bf16 GEMM for the out-projection: BM=128, BN=64 -> 504 blocks (2/CU).
// ---------------------------------------------------------------------------
__global__ __launch_bounds__(256) void gemm_bt2(
    const ushort* __restrict__ A, const ushort* __restrict__ B,
    const float* __restrict__ b0,
    float* __restrict__ C, int M, int N, int K)
{
    __shared__ ushort At[128 * 64];   // 16 KB
    __shared__ ushort Bt[64 * 64];    //  8 KB
    const int tid  = threadIdx.x;
    const int wave = tid >> 6, lane = tid & 63;
    const int m0 = blockIdx.x * 128, n0 = blockIdx.y * 64;
    const int wr = wave >> 1, wc = wave & 1;
    const int r = lane & 15, g = lane >> 4;
    const int srow = wave * 8 + (lane >> 3);
    const int scol = (lane & 7) * 8;
    const int brow[2] = { (0*256+tid)>>3, (1*256+tid)>>3 };
    const int bcol = (tid & 7) * 8;

    f32x4 acc[4][2] = {};

    for (int k0 = 0; k0 < K; k0 += 64) {
        const ushort* Ag = A + (size_t)m0 * K + k0;
        const ushort* Bg = B + (size_t)n0 * K + k0;
#pragma unroll
        for (int t = 0; t < 4; ++t)
            GLOAD16(Ag + (size_t)(t*32 + srow) * K + scol, &At[t*2048 + wave*512]);
#pragma unroll
        for (int t = 0; t < 2; ++t)
            GLOAD16(Bg + (size_t)brow[t] * K + bcol, &Bt[(t*256 + wave*64) * 8]);
        asm volatile("s_waitcnt vmcnt(0)" ::: "memory");
        __syncthreads();
#pragma unroll
        for (int kk = 0; kk < 2; ++kk) {
            bf16x8 af[4], bfr[2];
#pragma unroll
            for (int i = 0; i < 4; ++i)
                af[i] = *reinterpret_cast<const bf16x8*>(
                    &At[(wr*64 + i*16 + r) * 64 + kk*32 + g*8]);
#pragma unroll
            for (int i = 0; i < 2; ++i)
                bfr[i] = *reinterpret_cast<const bf16x8*>(
                    &Bt[(wc*32 + i*16 + r) * 64 + kk*32 + g*8]);
#pragma unroll
            for (int mi = 0; mi < 4; ++mi)
#pragma unroll
                for (int ni = 0; ni < 2; ++ni)
                    acc[mi][ni] = __builtin_amdgcn_mfma_f32_16x16x32_bf16(
                        af[mi], bfr[ni], acc[mi][ni], 0, 0, 0);
        }
        __syncthreads();
    }

#pragma unroll
    for (int ni = 0; ni < 2; ++ni) {
        int col = n0 + wc*32 + ni*16 + r;
        float bias = b0[col];
#pragma unroll
        for (int mi = 0; mi < 4; ++mi) {
            int row = m0 + wr*64 + mi*16 + g*4;
#pragma unroll
            for (int j = 0; j < 4; ++j)
                C[(size_t)(row + j) * N + col] = acc[mi][ni][j] + bias;
        }
    }
}

// ---------------------------------------------------------------------------
// 3) RMS-norm + RoPE for q,k from bf16 qkb; writes head-major bf16 [n][s][d].
//    1/sqrt(D)*log2(e) folded into q (exp2-domain softmax downstream).
// ---------------------------------------------------------------------------
__global__ __launch_bounds__(256) void normrope(
    const ushort* __restrict__ qkb, const int* __restrict__ gsz,
    const float* __restrict__ gq, const float* __restrict__ gk,
    const float* __restrict__ fcos, const float* __restrict__ fsin,
    ushort* __restrict__ q_r, ushort* __restrict__ k_r)
{
    const int s   = blockIdx.x;
    const int tid = threadIdx.x;
    const int wave = tid >> 6, lane = tid & 63;
    const uint* qrow = reinterpret_cast<const uint*>(qkb + (size_t)s * (2*DIM));
    const uint* krow = qrow + DIM/2;   // 768 uints = 1536 bf16

    float2 qv[3], kv[3];
    float sq = 0.f, sk = 0.f;
#pragma unroll
    for (int i = 0; i < 3; ++i) {
        int p = tid + i*256;
        uint uq = qrow[p], uk = krow[p];
        qv[i].x = bf2f(uq & 0xffffu); qv[i].y = bf2f(uq >> 16);
        kv[i].x = bf2f(uk & 0xffffu); kv[i].y = bf2f(uk >> 16);
        sq += qv[i].x*qv[i].x + qv[i].y*qv[i].y;
        sk += kv[i].x*kv[i].x + kv[i].y*kv[i].y;
    }
#pragma unroll
    for (int off = 1; off < 64; off <<= 1) {
        sq += __shfl_xor(sq, off);
        sk += __shfl_xor(sk, off);
    }
    __shared__ float red[4][2];
    if (lane == 0) { red[wave][0] = sq; red[wave][1] = sk; }
    __syncthreads();
    sq = red[0][0] + red[1][0] + red[2][0] + red[3][0];
    sk = red[0][1] + red[1][1] + red[2][1] + red[3][1];
    const float rmsq = rsqrtf(sq * (1.f/DIM) + 1e-6f);
    const float rmsk = rsqrtf(sk * (1.f/DIM) + 1e-6f);

    const int hh = gsz[1], ww = gsz[2];
    const int fidx = s / (hh*ww), rem = s % (hh*ww);
    const int hidx = rem / ww,  widx = rem % ww;
    // fold 1/sqrt(128) * log2(e): softmax runs in exp2 domain
    const float qscale = rmsq * (0.08838834764831845f * 1.4426950408889634f);

#pragma unroll
    for (int i = 0; i < 3; ++i) {
        int p = tid + i*256;               // pair index 0..767
        int c = p & 63, head = p >> 6;
        int coord = (c < 22) ? fidx : (c < 43) ? hidx : widx;
        float cv = fcos[coord*64 + c], sv = fsin[coord*64 + c];
        float2 gqv = reinterpret_cast<const float2*>(gq)[p];
        float2 gkv = reinterpret_cast<const float2*>(gk)[p];
        float a = qv[i].x * qscale * gqv.x, b = qv[i].y * qscale * gqv.y;
        uint qo = cvtpk(a*cv - b*sv, a*sv + b*cv);
        a = kv[i].x * rmsk * gkv.x; b = kv[i].y * rmsk * gkv.y;
        uint ko = cvtpk(a*cv - b*sv, a*sv + b*cv);
        size_t off = (((size_t)head * S_LEN + s) * HD + 2*c) >> 1;  // uint idx
        reinterpret_cast<uint*>(q_r)[off] = qo;
        reinterpret_cast<uint*>(k_r)[off] = ko;
    }
}

// ---------------------------------------------------------------------------
// 5) Flash attention, 32x32x16 MFMA with KEY-SPLIT wave pairs:
//    waves {2p,2p+1} share q-rows [blk*64+p*32, +32); wave khalf=w&1 handles
//    keys [kt*64+khalf*32, +32) of each staged 64-key tile. Same wave count
//    as 16x16 version (2016), but LDS reads/wave-iter drop 34 -> 16 b128 and
//    P never touches LDS (cvt_pk + permlane32_swap build, HW-verified R7).
//    End merge of the two partial (m,l,O) via freed Kl/Vl space.
//    K+V staged dbuf w/ XOR chunk swizzle (rows == lane mod 8 on all reads).
//    NOTE: V-direct-to-reg attempted twice (R10/R12) — compiler-defeated.
// ---------------------------------------------------------------------------
__global__ __launch_bounds__(256) void attn_fwd(
    const ushort* __restrict__ q_r, const ushort* __restrict__ k_r,
    const ushort* __restrict__ v_t, const int* __restrict__ seq_lens,
    ushort* __restrict__ attn_out)
{
    __shared__ ushort Kl[2][64 * 128];   // 2 x 16 KB (reused as merge Obuf)
    __shared__ ushort Vl[2][128 * 64];   // 2 x 16 KB (reused as merge MLbuf)
    const int tid  = threadIdx.x;
    const int wave = tid >> 6, lane = tid & 63;
    const int n  = blockIdx.y;
    const int seq = seq_lens[0];
    const int khalf = wave & 1, pair = wave >> 1;
    const int ql = lane & 31, h = lane >> 5, sw = lane & 7;
    const int qrow = blockIdx.x * 64 + pair * 32 + ql;
    const ushort* Qh = q_r + (size_t)n * S_LEN * HD;
    const ushort* Kh = k_r + (size_t)n * S_LEN * HD;
    const ushort* Vh = v_t + (size_t)n * HD * S_LEN;

    const int kj_row[4] = { (0*256+tid)>>4, (1*256+tid)>>4, (2*256+tid)>>4, (3*256+tid)>>4 };
    const int kj_w  = tid & 15;
    const int vj_d[4]  = { (0*256+tid)>>3, (1*256+tid)>>3, (2*256+tid)>>3, (3*256+tid)>>3 };
    const int vj_w  = tid & 7;

    bf16x8 qf[8];   // Q[qrow][c*16 + h*8 ..+7] (B-frag: col=q=ql, k=h*8+e)
#pragma unroll
    for (int c = 0; c < 8; ++c)
        qf[c] = *reinterpret_cast<const bf16x8*>(Qh + (size_t)qrow * HD + c*16 + h*8);

    f32x16 oacc[4] = {};   // oacc[db][j] = O[d=db*32+(j&3)+8*(j>>2)+4h][q=ql]
    float mrun = -1e30f, lrun = 0.f;

    const int nt = (seq + 63) >> 6;

#define STAGE(buf, kbase)                                                     \
    do {                                                                      \
        _Pragma("unroll")                                                     \
        for (int t = 0; t < 4; ++t) {                                         \
            int row = kj_row[t];                                              \
            GLOAD16(Kh + (size_t)((kbase) + row) * HD + ((kj_w ^ (row & 7)) * 8), \
                    &Kl[buf][(t*256 + wave*64) * 8]);                         \
        }                                                                     \
        _Pragma("unroll")                                                     \
        for (int t = 0; t < 4; ++t) {                                         \
            int d = vj_d[t];                                                  \
            GLOAD16(Vh + (size_t)d * S_LEN + (kbase) + ((vj_w ^ (d & 7)) * 8), \
                    &Vl[buf][(t*256 + wave*64) * 8]);                         \
        }                                                                     \
    } while (0)

    STAGE(0, 0);
    asm volatile("s_waitcnt vmcnt(0)" ::: "memory");
    __syncthreads();

    int cur = 0;
    for (int kt = 0; kt < nt; ++kt) {
        const int k0 = kt * 64 + khalf * 32;   // this wave's 32-key block
        if (kt + 1 < nt) STAGE(cur ^ 1, (kt+1) * 64);

        // ---- QK^T swapped (32x32x16): sf[j] = S[key=k0+(j&3)+8*(j>>2)+4h][q=ql]
        f32x16 sf = {};
        const ushort* kl = &Kl[cur][(khalf*32 + ql) * 128];
#pragma unroll
        for (int c = 0; c < 8; ++c)
            sf = __builtin_amdgcn_mfma_f32_32x32x16_bf16(
                *reinterpret_cast<const bf16x8*>(kl + ((2*c + h) ^ sw) * 8),
                qf[c], sf, 0, 0, 0);
        if (k0 + 32 > seq) {   // safety mask (S divisible by 64)
#pragma unroll
            for (int j = 0; j < 16; ++j)
                if (k0 + (j&3) + 8*(j>>2) + 4*h >= seq) sf[j] = -1e30f;
        }
        // ---- row max: 15-op in-lane tree + 1 shfl (combine h-halves)
        float pm = sf[0];
#pragma unroll
        for (int j = 1; j < 16; ++j) pm = fmaxf(pm, sf[j]);
        pm = fmaxf(pm, __shfl_xor(pm, 32));
        // ---- defer-max (THR=8, log2 domain)
        if (!__all(pm - mrun <= 8.f)) {
            float mn = fmaxf(mrun, pm);
            float scl = fexp2(mrun - mn);
            mrun = mn;
            lrun *= scl;
#pragma unroll
            for (int db = 0; db < 4; ++db)
#pragma unroll
                for (int j = 0; j < 16; ++j) oacc[db][j] *= scl;
        }
        // ---- P = exp2(S - mrun), in-lane sum + 1 shfl
        float ps = 0.f;
#pragma unroll
        for (int j = 0; j < 16; ++j) {
            float e = fexp2(sf[j] - mrun);
            sf[j] = e;
            ps += e;
        }
        ps += __shfl_xor(ps, 32);
        lrun += ps;
        // ---- P -> bf16 B-frags in-register (cvt_pk + permlane32_swap, R7)
        uint u0 = cvtpk(sf[0],  sf[1]),  u1 = cvtpk(sf[2],  sf[3]);
        uint u2 = cvtpk(sf[4],  sf[5]),  u3 = cvtpk(sf[6],  sf[7]);
        uint u4 = cvtpk(sf[8],  sf[9]),  u5 = cvtpk(sf[10], sf[11]);
        uint u6 = cvtpk(sf[12], sf[13]), u7 = cvtpk(sf[14], sf[15]);
        asm("v_permlane32_swap_b32 %0, %1" : "+v"(u0), "+v"(u2));
        asm("v_permlane32_swap_b32 %0, %1" : "+v"(u1), "+v"(u3));
        asm("v_permlane32_swap_b32 %0, %1" : "+v"(u4), "+v"(u6));
        asm("v_permlane32_swap_b32 %0, %1" : "+v"(u5), "+v"(u7));
        union { uint uu[4]; bf16x8 v; } fa, fb;
        fa.uu[0] = u0; fa.uu[1] = u1; fa.uu[2] = u2; fa.uu[3] = u3; // keys 0..15
        fb.uu[0] = u4; fb.uu[1] = u5; fb.uu[2] = u6; fb.uu[3] = u7; // keys 16..31
        // ---- PV swapped: oacc[db] += mfma(V_frag, P_frag) -> O[d][q]
#pragma unroll
        for (int db = 0; db < 4; ++db) {
            const ushort* vl = &Vl[cur][(db*32 + ql) * 64];
            oacc[db] = __builtin_amdgcn_mfma_f32_32x32x16_bf16(
                *reinterpret_cast<const bf16x8*>(vl + ((khalf*4 + 0 + h) ^ sw) * 8),
                fa.v, oacc[db], 0, 0, 0);
            oacc[db] = __builtin_amdgcn_mfma_f32_32x32x16_bf16(
                *reinterpret_cast<const bf16x8*>(vl + ((khalf*4 + 2 + h) ^ sw) * 8),
                fb.v, oacc[db], 0, 0, 0);
        }

        if (kt + 1 < nt) {
            asm volatile("s_waitcnt vmcnt(0)" ::: "memory");
            __syncthreads();
            cur ^= 1;
        }
    }
#undef STAGE

    // ---- merge the two key-halves of each wave pair via freed LDS
    __syncthreads();
    float* Obuf  = (float*)&Kl[0][0];   // [2 pairs][128 d][32 q] = 8192 f32
    float* MLbuf = (float*)&Vl[0][0];   // [2 pairs][{m,l}][32 q]
    if (khalf == 1) {
#pragma unroll
        for (int db = 0; db < 4; ++db)
#pragma unroll
            for (int j = 0; j < 16; ++j) {
                int d = db*32 + (j&3) + 8*(j>>2) + 4*h;
                Obuf[pair*4096 + d*32 + ql] = oacc[db][j];
            }
        if (h == 0) { MLbuf[pair*64 + ql] = mrun; MLbuf[pair*64 + 32 + ql] = lrun; }
    }
    __syncthreads();
    if (khalf == 0) {
        float m2 = MLbuf[pair*64 + ql], l2 = MLbuf[pair*64 + 32 + ql];
        float mm = fmaxf(mrun, m2);
        float s1 = fexp2(mrun - mm), s2 = fexp2(m2 - mm);
        float ltot = lrun * s1 + l2 * s2;
        float inv = (ltot > 0.f) ? 1.f / ltot : 0.f;
#pragma unroll
        for (int db = 0; db < 4; ++db)
#pragma unroll
            for (int j = 0; j < 16; ++j) {
                int d = db*32 + (j&3) + 8*(j>>2) + 4*h;
                oacc[db][j] = (oacc[db][j] * s1 +
                               Obuf[pair*4096 + d*32 + ql] * s2) * inv;
            }
        // store 16x b64: d = db*32 + 8*jg + 4h + (0..3), row qrow
#pragma unroll
        for (int db = 0; db < 4; ++db)
#pragma unroll
            for (int jg = 0; jg < 4; ++jg) {
                uint2 pkt;
                pkt.x = cvtpk(oacc[db][jg*4+0], oacc[db][jg*4+1]);
                pkt.y = cvtpk(oacc[db][jg*4+2], oacc[db][jg*4+3]);
                *reinterpret_cast<uint2*>(
                    &attn_out[(size_t)qrow * DIM + n*HD + db*32 + jg*8 + 4*h]) = pkt;
            }
    }
}

// ---------------------------------------------------------------------------
extern "C" void kernel_launch(void* const* d_in, const int* in_sizes, int n_in,
                              void* d_out, int out_size, void* d_ws, size_t ws_size,
                              hipStream_t stream)
{
    const float* x    = (const float*)d_in[0];
    const int*   seqL = (const int*)  d_in[1];
    const int*   gsz  = (const int*)  d_in[2];
    const float* fcos = (const float*)d_in[3];
    const float* fsin = (const float*)d_in[4];
    const float* Wq   = (const float*)d_in[5];
    const float* bq   = (const float*)d_in[6];
    const float* Wk   = (const float*)d_in[7];
    const float* bk   = (const float*)d_in[8];
    const float* Wv   = (const float*)d_in[9];
    const float* bv   = (const float*)d_in[10];
    const float* Wo   = (const float*)d_in[11];
    const float* bo   = (const float*)d_in[12];
    const float* gq   = (const float*)d_in[13];
    const float* gk   = (const float*)d_in[14];
    float* out = (float*)d_out;

    char* ws = (char*)d_ws;
    ushort* xb  = (ushort*)ws;                     // S*DIM         =  8.26 MB
    ushort* wb  = xb  + (size_t)S_LEN * DIM;       // 4*DIM*DIM     = 18.87 MB
    ushort* qkb = wb  + 4*(size_t)DIM*DIM;         // S*3072        = 16.52 MB
    ushort* v_t = qkb + (size_t)S_LEN * 2*DIM;     // DIM*S         =  8.26 MB
    ushort* q_r = v_t + (size_t)DIM * S_LEN;       // S*DIM         =  8.26 MB
    ushort* k_r = q_r + (size_t)S_LEN * DIM;       // S*DIM         =  8.26 MB
    ushort* ao  = k_r + (size_t)S_LEN * DIM;       // S*DIM         =  8.26 MB
    // total ws use: ~76.7 MB

    convert_all<<<13248, 256, 0, stream>>>(x, Wq, Wk, Wv, Wo, xb, wb);
    gemm_qkv<<<dim3(21, 36), 256, 0, stream>>>(xb, wb, bq, bk, bv,
                                               qkb, v_t, DIM);
    normrope<<<S_LEN, 256, 0, stream>>>(qkb, gsz, gq, gk, fcos, fsin, q_r, k_r);
    attn_fwd<<<dim3(42, 12), 256, 0, stream>>>(q_r, k_r, v_t, seqL, ao);
    gemm_bt2<<<dim3(21, 24), 256, 0, stream>>>(ao, wb + 3*(size_t)DIM*DIM,
                                               bo, out, S_LEN, DIM, DIM);
}

// Round 15
// 192.866 us; speedup vs baseline: 1.9093x; 1.0824x over previous
//
#include <hip/hip_runtime.h>
#include <hip/hip_bf16.h>
#include <stdint.h>

#define S_LEN 2688
#define DIM   1536
#define NH    12
#define HD    128
#define QKV_N 4608   // 3*DIM

typedef __attribute__((ext_vector_type(8)))  short bf16x8;
typedef __attribute__((ext_vector_type(4)))  float f32x4;
typedef __attribute__((ext_vector_type(16))) float f32x16;

__device__ inline ushort f2bf(float f) {
    uint32_t u = __float_as_uint(f);
    uint32_t r = (u + 0x7fffu + ((u >> 16) & 1u)) >> 16;
    return (ushort)r;
}
__device__ inline float bf2f(uint u) { return __uint_as_float(u << 16); }
__device__ inline float fexp2(float x) {           // raw v_exp_f32 (2^x); args
    float r;                                       // bounded by defer-max
    asm("v_exp_f32 %0, %1" : "=v"(r) : "v"(x));
    return r;
}
__device__ inline uint cvtpk(float lo, float hi) { // 2xf32 -> packed bf16
    uint r;
    asm("v_cvt_pk_bf16_f32 %0, %1, %2" : "=v"(r) : "v"(lo), "v"(hi));
    return r;
}

#define GLOAD16(gp, lp) __builtin_amdgcn_global_load_lds( \
    (__attribute__((address_space(1))) const void*)(gp),  \
    (__attribute__((address_space(3))) void*)(lp), 16, 0, 0)

// ---------------------------------------------------------------------------
// 1) fp32 -> bf16 convert: x and the four weight matrices (fused into wb)
// ---------------------------------------------------------------------------
__global__ __launch_bounds__(256) void convert_all(
    const float* __restrict__ x,
    const float* __restrict__ wq, const float* __restrict__ wk,
    const float* __restrict__ wv, const float* __restrict__ wo,
    ushort* __restrict__ xb, ushort* __restrict__ wb)
{
    const size_t NX4 = (size_t)S_LEN * DIM / 4;   // 1,032,192
    const size_t NW4 = (size_t)DIM * DIM / 4;     //   589,824
    size_t i = (size_t)blockIdx.x * 256 + threadIdx.x;
    const float* src; ushort* dst;
    if (i < NX4)            { src = x;  dst = xb; }
    else if (i < NX4+1*NW4) { src = wq; dst = wb;                        i -= NX4; }
    else if (i < NX4+2*NW4) { src = wk; dst = wb + 1*(size_t)DIM*DIM;    i -= NX4+1*NW4; }
    else if (i < NX4+3*NW4) { src = wv; dst = wb + 2*(size_t)DIM*DIM;    i -= NX4+2*NW4; }
    else if (i < NX4+4*NW4) { src = wo; dst = wb + 3*(size_t)DIM*DIM;    i -= NX4+3*NW4; }
    else return;
    float4 v = reinterpret_cast<const float4*>(src)[i];
    ushort4 o = { f2bf(v.x), f2bf(v.y), f2bf(v.z), f2bf(v.w) };
    reinterpret_cast<ushort4*>(dst)[i] = o;
}

// ---------------------------------------------------------------------------
// 2) QKV GEMM, bf16 out: q/k -> qkb [S][3072]; V -> v_t [d][S] transposed.
//    128x128 tile, BK=64, 4 waves (2x2), 16x16x32 MFMA.
//    R15: DOUBLE-BUFFERED staging (T3-minimum 2-phase: STAGE(t+1) issued
//    before compute(t), one vmcnt(0)+barrier per K-step) + both-sides XOR
//    chunk swizzle (source chunk w^(row&7), read chunk ^(r&7)) — the staging
//    recipe HW-verified 5x in attn_fwd. 64 KB LDS -> 2 blocks/CU.
//    XCD chunk-swizzle (T1, m204 bijective: nwg=756, q=94, r=4).
// ---------------------------------------------------------------------------
__global__ __launch_bounds__(256) void gemm_qkv(
    const ushort* __restrict__ A, const ushort* __restrict__ B,
    const float* __restrict__ bq, const float* __restrict__ bk,
    const float* __restrict__ bv,
    ushort* __restrict__ qkb, ushort* __restrict__ v_t, int K)
{
    __shared__ ushort At[2][128 * 64];   // 2 x 16 KB
    __shared__ ushort Bt[2][128 * 64];   // 2 x 16 KB
    const int tid  = threadIdx.x;
    const int wave = tid >> 6, lane = tid & 63;
    // m204 bijective XCD swizzle of the 756-block grid (x fastest)
    const int lid  = blockIdx.y * 21 + blockIdx.x;
    const int xcd  = lid & 7, pos = lid >> 3;
    const int wgid = (xcd < 4 ? xcd * 95 : 4 * 95 + (xcd - 4) * 94) + pos;
    const int m0 = (wgid % 21) * 128, n0 = (wgid / 21) * 128;
    const int wr = wave >> 1, wc = wave & 1;
    const int r = lane & 15, g = lane >> 4;
    const int swz = r & 7;
    // staging chunk indices: chunk j = t*256+tid, row = j>>3, w = tid&7
    const int sj_row[4] = { (0*256+tid)>>3, (1*256+tid)>>3,
                            (2*256+tid)>>3, (3*256+tid)>>3 };
    const int sj_w = tid & 7;

    f32x4 acc[4][4] = {};
    const int NT = K >> 6;   // 24

#define STAGE_G(buf, kb)                                                      \
    do {                                                                      \
        const ushort* Ag = A + (size_t)m0 * K + (kb);                         \
        const ushort* Bg = B + (size_t)n0 * K + (kb);                         \
        _Pragma("unroll")                                                     \
        for (int t = 0; t < 4; ++t) {                                         \
            int row = sj_row[t];                                              \
            GLOAD16(Ag + (size_t)row * K + ((sj_w ^ (row & 7)) * 8),          \
                    &At[buf][(t*256 + tid) * 8]);                             \
        }                                                                     \
        _Pragma("unroll")                                                     \
        for (int t = 0; t < 4; ++t) {                                         \
            int row = sj_row[t];                                              \
            GLOAD16(Bg + (size_t)row * K + ((sj_w ^ (row & 7)) * 8),          \
                    &Bt[buf][(t*256 + tid) * 8]);                             \
        }                                                                     \
    } while (0)

    STAGE_G(0, 0);
    asm volatile("s_waitcnt vmcnt(0)" ::: "memory");
    __syncthreads();

    int cur = 0;
    for (int kt = 0; kt < NT; ++kt) {
        if (kt + 1 < NT) STAGE_G(cur ^ 1, (kt+1) * 64);
#pragma unroll
        for (int kk = 0; kk < 2; ++kk) {
            bf16x8 af[4], bfr[4];
#pragma unroll
            for (int i = 0; i < 4; ++i)
                af[i] = *reinterpret_cast<const bf16x8*>(
                    &At[cur][(wr*64 + i*16 + r) * 64 + ((kk*4 + g) ^ swz) * 8]);
#pragma unroll
            for (int i = 0; i < 4; ++i)
                bfr[i] = *reinterpret_cast<const bf16x8*>(
                    &Bt[cur][(wc*64 + i*16 + r) * 64 + ((kk*4 + g) ^ swz) * 8]);
#pragma unroll
            for (int mi = 0; mi < 4; ++mi)
#pragma unroll
                for (int ni = 0; ni < 4; ++ni)
                    acc[mi][ni] = __builtin_amdgcn_mfma_f32_16x16x32_bf16(
                        af[mi], bfr[ni], acc[mi][ni], 0, 0, 0);
        }
        if (kt + 1 < NT) {
            asm volatile("s_waitcnt vmcnt(0)" ::: "memory");
            __syncthreads();
            cur ^= 1;
        }
    }
#undef STAGE_G

    if (n0 < 2*DIM) {       // q/k region (block-uniform branch)
#pragma unroll
        for (int ni = 0; ni < 4; ++ni) {
            int col = n0 + wc*64 + ni*16 + r;
            float bias = (col < DIM) ? bq[col] : bk[col - DIM];
#pragma unroll
            for (int mi = 0; mi < 4; ++mi) {
                int row = m0 + wr*64 + mi*16 + g*4;
#pragma unroll
                for (int j = 0; j < 4; ++j)
                    qkb[(size_t)(row + j) * (2*DIM) + col] =
                        f2bf(acc[mi][ni][j] + bias);
            }
        }
    } else {                // V region: transposed 8B stores into v_t[d][s]
#pragma unroll
        for (int ni = 0; ni < 4; ++ni) {
            int d = n0 - 2*DIM + wc*64 + ni*16 + r;
            float bias = bv[d];
#pragma unroll
            for (int mi = 0; mi < 4; ++mi) {
                int row = m0 + wr*64 + mi*16 + g*4;
                uint2 pkt;
                pkt.x = cvtpk(acc[mi][ni][0] + bias, acc[mi][ni][1] + bias);
                pkt.y = cvtpk(acc[mi][ni][2] + bias, acc[mi][ni][3] + bias);
                *reinterpret_cast<uint2*>(&v_t[(size_t)d * S_LEN + row]) = pkt;
            }
        }
    }
}

// ---------------------------------------------------------------------------
// 2b) bf16 GEMM for the out-projection: BM=128, BN=64 -> 504 blocks (2/CU).
// ---------------------------------------------------------------------------
__global__ __launch_bounds__(256) void gemm_bt2(
    const ushort* __restrict__ A, const ushort* __restrict__ B,
    const float* __restrict__ b0,
    float* __restrict__ C, int M, int N, int K)
{
    __shared__ ushort At[128 * 64];   // 16 KB
    __shared__ ushort Bt[64 * 64];    //  8 KB
    const int tid  = threadIdx.x;
    const int wave = tid >> 6, lane = tid & 63;
    const int m0 = blockIdx.x * 128, n0 = blockIdx.y * 64;
    const int wr = wave >> 1, wc = wave & 1;
    const int r = lane & 15, g = lane >> 4;
    const int srow = wave * 8 + (lane >> 3);
    const int scol = (lane & 7) * 8;
    const int brow[2] = { (0*256+tid)>>3, (1*256+tid)>>3 };
    const int bcol = (tid & 7) * 8;

    f32x4 acc[4][2] = {};

    for (int k0 = 0; k0 < K; k0 += 64) {
        const ushort* Ag = A + (size_t)m0 * K + k0;
        const ushort* Bg = B + (size_t)n0 * K + k0;
#pragma unroll
        for (int t = 0; t < 4; ++t)
            GLOAD16(Ag + (size_t)(t*32 + srow) * K + scol, &At[t*2048 + wave*512]);
#pragma unroll
        for (int t = 0; t < 2; ++t)
            GLOAD16(Bg + (size_t)brow[t] * K + bcol, &Bt[(t*256 + wave*64) * 8]);
        asm volatile("s_waitcnt vmcnt(0)" ::: "memory");
        __syncthreads();
#pragma unroll
        for (int kk = 0; kk < 2; ++kk) {
            bf16x8 af[4], bfr[2];
#pragma unroll
            for (int i = 0; i < 4; ++i)
                af[i] = *reinterpret_cast<const bf16x8*>(
                    &At[(wr*64 + i*16 + r) * 64 + kk*32 + g*8]);
#pragma unroll
            for (int i = 0; i < 2; ++i)
                bfr[i] = *reinterpret_cast<const bf16x8*>(
                    &Bt[(wc*32 + i*16 + r) * 64 + kk*32 + g*8]);
#pragma unroll
            for (int mi = 0; mi < 4; ++mi)
#pragma unroll
                for (int ni = 0; ni < 2; ++ni)
                    acc[mi][ni] = __builtin_amdgcn_mfma_f32_16x16x32_bf16(
                        af[mi], bfr[ni], acc[mi][ni], 0, 0, 0);
        }
        __syncthreads();
    }

#pragma unroll
    for (int ni = 0; ni < 2; ++ni) {
        int col = n0 + wc*32 + ni*16 + r;
        float bias = b0[col];
#pragma unroll
        for (int mi = 0; mi < 4; ++mi) {
            int row = m0 + wr*64 + mi*16 + g*4;
#pragma unroll
            for (int j = 0; j < 4; ++j)
                C[(size_t)(row + j) * N + col] = acc[mi][ni][j] + bias;
        }
    }
}

// ---------------------------------------------------------------------------
// 3) RMS-norm + RoPE for q,k from bf16 qkb; writes head-major bf16 [n][s][d].
//    1/sqrt(D)*log2(e) folded into q (exp2-domain softmax downstream).
// ---------------------------------------------------------------------------
__global__ __launch_bounds__(256) void normrope(
    const ushort* __restrict__ qkb, const int* __restrict__ gsz,
    const float* __restrict__ gq, const float* __restrict__ gk,
    const float* __restrict__ fcos, const float* __restrict__ fsin,
    ushort* __restrict__ q_r, ushort* __restrict__ k_r)
{
    const int s   = blockIdx.x;
    const int tid = threadIdx.x;
    const int wave = tid >> 6, lane = tid & 63;
    const uint* qrow = reinterpret_cast<const uint*>(qkb + (size_t)s * (2*DIM));
    const uint* krow = qrow + DIM/2;   // 768 uints = 1536 bf16

    float2 qv[3], kv[3];
    float sq = 0.f, sk = 0.f;
#pragma unroll
    for (int i = 0; i < 3; ++i) {
        int p = tid + i*256;
        uint uq = qrow[p], uk = krow[p];
        qv[i].x = bf2f(uq & 0xffffu); qv[i].y = bf2f(uq >> 16);
        kv[i].x = bf2f(uk & 0xffffu); kv[i].y = bf2f(uk >> 16);
        sq += qv[i].x*qv[i].x + qv[i].y*qv[i].y;
        sk += kv[i].x*kv[i].x + kv[i].y*kv[i].y;
    }
#pragma unroll
    for (int off = 1; off < 64; off <<= 1) {
        sq += __shfl_xor(sq, off);
        sk += __shfl_xor(sk, off);
    }
    __shared__ float red[4][2];
    if (lane == 0) { red[wave][0] = sq; red[wave][1] = sk; }
    __syncthreads();
    sq = red[0][0] + red[1][0] + red[2][0] + red[3][0];
    sk = red[0][1] + red[1][1] + red[2][1] + red[3][1];
    const float rmsq = rsqrtf(sq * (1.f/DIM) + 1e-6f);
    const float rmsk = rsqrtf(sk * (1.f/DIM) + 1e-6f);

    const int hh = gsz[1], ww = gsz[2];
    const int fidx = s / (hh*ww), rem = s % (hh*ww);
    const int hidx = rem / ww,  widx = rem % ww;
    // fold 1/sqrt(128) * log2(e): softmax runs in exp2 domain
    const float qscale = rmsq * (0.08838834764831845f * 1.4426950408889634f);

#pragma unroll
    for (int i = 0; i < 3; ++i) {
        int p = tid + i*256;               // pair index 0..767
        int c = p & 63, head = p >> 6;
        int coord = (c < 22) ? fidx : (c < 43) ? hidx : widx;
        float cv = fcos[coord*64 + c], sv = fsin[coord*64 + c];
        float2 gqv = reinterpret_cast<const float2*>(gq)[p];
        float2 gkv = reinterpret_cast<const float2*>(gk)[p];
        float a = qv[i].x * qscale * gqv.x, b = qv[i].y * qscale * gqv.y;
        uint qo = cvtpk(a*cv - b*sv, a*sv + b*cv);
        a = kv[i].x * rmsk * gkv.x; b = kv[i].y * rmsk * gkv.y;
        uint ko = cvtpk(a*cv - b*sv, a*sv + b*cv);
        size_t off = (((size_t)head * S_LEN + s) * HD + 2*c) >> 1;  // uint idx
        reinterpret_cast<uint*>(q_r)[off] = qo;
        reinterpret_cast<uint*>(k_r)[off] = ko;
    }
}

// ---------------------------------------------------------------------------
// 5) Flash attention, 32x32x16 MFMA with KEY-SPLIT wave pairs (R14-verified):
//    waves {2p,2p+1} share q-rows; wave khalf=w&1 handles keys
//    [kt*64+khalf*32, +32). LDS reads/wave-iter 16 b128, P in-register
//    (cvt_pk + permlane32_swap). End merge via freed Kl/Vl space.
//    K+V staged dbuf w/ XOR chunk swizzle.
//    NOTE: V-direct-to-reg attempted twice (R10/R12) — compiler-defeated.
// ---------------------------------------------------------------------------
__global__ __launch_bounds__(256) void attn_fwd(
    const ushort* __restrict__ q_r, const ushort* __restrict__ k_r,
    const ushort* __restrict__ v_t, const int* __restrict__ seq_lens,
    ushort* __restrict__ attn_out)
{
    __shared__ ushort Kl[2][64 * 128];   // 2 x 16 KB (reused as merge Obuf)
    __shared__ ushort Vl[2][128 * 64];   // 2 x 16 KB (reused as merge MLbuf)
    const int tid  = threadIdx.x;
    const int wave = tid >> 6, lane = tid & 63;
    const int n  = blockIdx.y;
    const int seq = seq_lens[0];
    const int khalf = wave & 1, pair = wave >> 1;
    const int ql = lane & 31, h = lane >> 5, sw = lane & 7;
    const int qrow = blockIdx.x * 64 + pair * 32 + ql;
    const ushort* Qh = q_r + (size_t)n * S_LEN * HD;
    const ushort* Kh = k_r + (size_t)n * S_LEN * HD;
    const ushort* Vh = v_t + (size_t)n * HD * S_LEN;

    const int kj_row[4] = { (0*256+tid)>>4, (1*256+tid)>>4, (2*256+tid)>>4, (3*256+tid)>>4 };
    const int kj_w  = tid & 15;
    const int vj_d[4]  = { (0*256+tid)>>3, (1*256+tid)>>3, (2*256+tid)>>3, (3*256+tid)>>3 };
    const int vj_w  = tid & 7;

    bf16x8 qf[8];   // Q[qrow][c*16 + h*8 ..+7] (B-frag: col=q=ql, k=h*8+e)
#pragma unroll
    for (int c = 0; c < 8; ++c)
        qf[c] = *reinterpret_cast<const bf16x8*>(Qh + (size_t)qrow * HD + c*16 + h*8);

    f32x16 oacc[4] = {};   // oacc[db][j] = O[d=db*32+(j&3)+8*(j>>2)+4h][q=ql]
    float mrun = -1e30f, lrun = 0.f;

    const int nt = (seq + 63) >> 6;

#define STAGE(buf, kbase)                                                     \
    do {                                                                      \
        _Pragma("unroll")                                                     \
        for (int t = 0; t < 4; ++t) {                                         \
            int row = kj_row[t];                                              \
            GLOAD16(Kh + (size_t)((kbase) + row) * HD + ((kj_w ^ (row & 7)) * 8), \
                    &Kl[buf][(t*256 + wave*64) * 8]);                         \
        }                                                                     \
        _Pragma("unroll")                                                     \
        for (int t = 0; t < 4; ++t) {                                         \
            int d = vj_d[t];                                                  \
            GLOAD16(Vh + (size_t)d * S_LEN + (kbase) + ((vj_w ^ (d & 7)) * 8), \
                    &Vl[buf][(t*256 + wave*64) * 8]);                         \
        }                                                                     \
    } while (0)

    STAGE(0, 0);
    asm volatile("s_waitcnt vmcnt(0)" ::: "memory");
    __syncthreads();

    int cur = 0;
    for (int kt = 0; kt < nt; ++kt) {
        const int k0 = kt * 64 + khalf * 32;   // this wave's 32-key block
        if (kt + 1 < nt) STAGE(cur ^ 1, (kt+1) * 64);

        // ---- QK^T swapped (32x32x16): sf[j] = S[key=k0+(j&3)+8*(j>>2)+4h][q=ql]
        f32x16 sf = {};
        const ushort* kl = &Kl[cur][(khalf*32 + ql) * 128];
#pragma unroll
        for (int c = 0; c < 8; ++c)
            sf = __builtin_amdgcn_mfma_f32_32x32x16_bf16(
                *reinterpret_cast<const bf16x8*>(kl + ((2*c + h) ^ sw) * 8),
                qf[c], sf, 0, 0, 0);
        if (k0 + 32 > seq) {   // safety mask (S divisible by 64)
#pragma unroll
            for (int j = 0; j < 16; ++j)
                if (k0 + (j&3) + 8*(j>>2) + 4*h >= seq) sf[j] = -1e30f;
        }
        // ---- row max: 15-op in-lane tree + 1 shfl (combine h-halves)
        float pm = sf[0];
#pragma unroll
        for (int j = 1; j < 16; ++j) pm = fmaxf(pm, sf[j]);
        pm = fmaxf(pm, __shfl_xor(pm, 32));
        // ---- defer-max (THR=8, log2 domain)
        if (!__all(pm - mrun <= 8.f)) {
            float mn = fmaxf(mrun, pm);
            float scl = fexp2(mrun - mn);
            mrun = mn;
            lrun *= scl;
#pragma unroll
            for (int db = 0; db < 4; ++db)
#pragma unroll
                for (int j = 0; j < 16; ++j) oacc[db][j] *= scl;
        }
        // ---- P = exp2(S - mrun), in-lane sum + 1 shfl
        float ps = 0.f;
#pragma unroll
        for (int j = 0; j < 16; ++j) {
            float e = fexp2(sf[j] - mrun);
            sf[j] = e;
            ps += e;
        }
        ps += __shfl_xor(ps, 32);
        lrun += ps;
        // ---- P -> bf16 B-frags in-register (cvt_pk + permlane32_swap, R7)
        uint u0 = cvtpk(sf[0],  sf[1]),  u1 = cvtpk(sf[2],  sf[3]);
        uint u2 = cvtpk(sf[4],  sf[5]),  u3 = cvtpk(sf[6],  sf[7]);
        uint u4 = cvtpk(sf[8],  sf[9]),  u5 = cvtpk(sf[10], sf[11]);
        uint u6 = cvtpk(sf[12], sf[13]), u7 = cvtpk(sf[14], sf[15]);
        asm("v_permlane32_swap_b32 %0, %1" : "+v"(u0), "+v"(u2));
        asm("v_permlane32_swap_b32 %0, %1" : "+v"(u1), "+v"(u3));
        asm("v_permlane32_swap_b32 %0, %1" : "+v"(u4), "+v"(u6));
        asm("v_permlane32_swap_b32 %0, %1" : "+v"(u5), "+v"(u7));
        union { uint uu[4]; bf16x8 v; } fa, fb;
        fa.uu[0] = u0; fa.uu[1] = u1; fa.uu[2] = u2; fa.uu[3] = u3; // keys 0..15
        fb.uu[0] = u4; fb.uu[1] = u5; fb.uu[2] = u6; fb.uu[3] = u7; // keys 16..31
        // ---- PV swapped: oacc[db] += mfma(V_frag, P_frag) -> O[d][q]
#pragma unroll
        for (int db = 0; db < 4; ++db) {
            const ushort* vl = &Vl[cur][(db*32 + ql) * 64];
            oacc[db] = __builtin_amdgcn_mfma_f32_32x32x16_bf16(
                *reinterpret_cast<const bf16x8*>(vl + ((khalf*4 + 0 + h) ^ sw) * 8),
                fa.v, oacc[db], 0, 0, 0);
            oacc[db] = __builtin_amdgcn_mfma_f32_32x32x16_bf16(
                *reinterpret_cast<const bf16x8*>(vl + ((khalf*4 + 2 + h) ^ sw) * 8),
                fb.v, oacc[db], 0, 0, 0);
        }

        if (kt + 1 < nt) {
            asm volatile("s_waitcnt vmcnt(0)" ::: "memory");
            __syncthreads();
            cur ^= 1;
        }
    }
#undef STAGE

    // ---- merge the two key-halves of each wave pair via freed LDS
    __syncthreads();
    float* Obuf  = (float*)&Kl[0][0];   // [2 pairs][128 d][32 q] = 8192 f32
    float* MLbuf = (float*)&Vl[0][0];   // [2 pairs][{m,l}][32 q]
    if (khalf == 1) {
#pragma unroll
        for (int db = 0; db < 4; ++db)
#pragma unroll
            for (int j = 0; j < 16; ++j) {
                int d = db*32 + (j&3) + 8*(j>>2) + 4*h;
                Obuf[pair*4096 + d*32 + ql] = oacc[db][j];
            }
        if (h == 0) { MLbuf[pair*64 + ql] = mrun; MLbuf[pair*64 + 32 + ql] = lrun; }
    }
    __syncthreads();
    if (khalf == 0) {
        float m2 = MLbuf[pair*64 + ql], l2 = MLbuf[pair*64 + 32 + ql];
        float mm = fmaxf(mrun, m2);
        float s1 = fexp2(mrun - mm), s2 = fexp2(m2 - mm);
        float ltot = lrun * s1 + l2 * s2;
        float inv = (ltot > 0.f) ? 1.f / ltot : 0.f;
#pragma unroll
        for (int db = 0; db < 4; ++db)
#pragma unroll
            for (int j = 0; j < 16; ++j) {
                int d = db*32 + (j&3) + 8*(j>>2) + 4*h;
                oacc[db][j] = (oacc[db][j] * s1 +
                               Obuf[pair*4096 + d*32 + ql] * s2) * inv;
            }
        // store 16x b64: d = db*32 + 8*jg + 4h + (0..3), row qrow
#pragma unroll
        for (int db = 0; db < 4; ++db)
#pragma unroll
            for (int jg = 0; jg < 4; ++jg) {
                uint2 pkt;
                pkt.x = cvtpk(oacc[db][jg*4+0], oacc[db][jg*4+1]);
                pkt.y = cvtpk(oacc[db][jg*4+2], oacc[db][jg*4+3]);
                *reinterpret_cast<uint2*>(
                    &attn_out[(size_t)qrow * DIM + n*HD + db*32 + jg*8 + 4*h]) = pkt;
            }
    }
}

// ---------------------------------------------------------------------------
extern "C" void kernel_launch(void* const* d_in, const int* in_sizes, int n_in,
                              void* d_out, int out_size, void* d_ws, size_t ws_size,
                              hipStream_t stream)
{
    const float* x    = (const float*)d_in[0];
    const int*   seqL = (const int*)  d_in[1];
    const int*   gsz  = (const int*)  d_in[2];
    const float* fcos = (const float*)d_in[3];
    const float* fsin = (const float*)d_in[4];
    const float* Wq   = (const float*)d_in[5];
    const float* bq   = (const float*)d_in[6];
    const float* Wk   = (const float*)d_in[7];
    const float* bk   = (const float*)d_in[8];
    const float* Wv   = (const float*)d_in[9];
    const float* bv   = (const float*)d_in[10];
    const float* Wo   = (const float*)d_in[11];
    const float* bo   = (const float*)d_in[12];
    const float* gq   = (const float*)d_in[13];
    const float* gk   = (const float*)d_in[14];
    float* out = (float*)d_out;

    char* ws = (char*)d_ws;
    ushort* xb  = (ushort*)ws;                     // S*DIM         =  8.26 MB
    ushort* wb  = xb  + (size_t)S_LEN * DIM;       // 4*DIM*DIM     = 18.87 MB
    ushort* qkb = wb  + 4*(size_t)DIM*DIM;         // S*3072        = 16.52 MB
    ushort* v_t = qkb + (size_t)S_LEN * 2*DIM;     // DIM*S         =  8.26 MB
    ushort* q_r = v_t + (size_t)DIM * S_LEN;       // S*DIM         =  8.26 MB
    ushort* k_r = q_r + (size_t)S_LEN * DIM;       // S*DIM         =  8.26 MB
    ushort* ao  = k_r + (size_t)S_LEN * DIM;       // S*DIM         =  8.26 MB
    // total ws use: ~76.7 MB

    convert_all<<<13248, 256, 0, stream>>>(x, Wq, Wk, Wv, Wo, xb, wb);
    gemm_qkv<<<dim3(21, 36), 256, 0, stream>>>(xb, wb, bq, bk, bv,
                                               qkb, v_t, DIM);
    normrope<<<S_LEN, 256, 0, stream>>>(qkb, gsz, gq, gk, fcos, fsin, q_r, k_r);
    attn_fwd<<<dim3(42, 12), 256, 0, stream>>>(q_r, k_r, v_t, seqL, ao);
    gemm_bt2<<<dim3(21, 24), 256, 0, stream>>>(ao, wb + 3*(size_t)DIM*DIM,
                                               bo, out, S_LEN, DIM, DIM);
}